// Round 6
// baseline (1090.791 us; speedup 1.0000x reference)
//
#include <hip/hip_runtime.h>
#include <hip/hip_bf16.h>
#include <math.h>

#define PDIM 10
#define HDIM 128
#define TDIM 138   // PDIM + HDIM

// converted-weights layout (fp32, in ws)
#define CW_WQ 0
#define CW_WK 17664
#define CW_WV 35328
#define CW_WO 51712
#define CW_BQ 68096
#define CW_BK 68224
#define CW_BV 68352
#define CW_BO 68480
#define CW_GA 68608
#define CW_BE 68736
#define CW_TOTAL 68864

// ---------- bf16 helpers (raw ushort representation) ----------
__device__ __forceinline__ float b2f_lo(unsigned u) { return __uint_as_float(u << 16); }
__device__ __forceinline__ float b2f_hi(unsigned u) { return __uint_as_float(u & 0xffff0000u); }
__device__ __forceinline__ unsigned short f2b(float f) {
    unsigned u = __float_as_uint(f);
    u += 0x7fffu + ((u >> 16) & 1u);   // round-to-nearest-even
    return (unsigned short)(u >> 16);
}
__device__ __forceinline__ void store4bf(unsigned short* p, float a, float b, float c, float d) {
    ushort4 v; v.x = f2b(a); v.y = f2b(b); v.z = f2b(c); v.w = f2b(d);
    *(ushort4*)p = v;
}

// ws-too-small sentinel (fp32 out[0] = ~1.27e30 * (1 + bucket/256))
__global__ void ws_sentinel_kernel(float* out, int bucket)
{
    if (threadIdx.x == 0) out[0] = ldexpf(1.f + (float)bucket / 256.f, 100);
}

// =====================================================================
// K0: copy weights/biases/gamma/beta (fp32) into one contiguous block.
// =====================================================================
__global__ __launch_bounds__(256) void convert_weights(
    const float* Wq, const float* Wk, const float* Wv, const float* Wo,
    const float* bq, const float* bk, const float* bv, const float* bo,
    const float* ga, const float* be,
    float* __restrict__ dst)
{
    int idx = blockIdx.x * 256 + threadIdx.x;
    if (idx >= CW_TOTAL) return;
    const float* src; int loc;
    if      (idx < CW_WK) { src = Wq; loc = idx - CW_WQ; }
    else if (idx < CW_WV) { src = Wk; loc = idx - CW_WK; }
    else if (idx < CW_WO) { src = Wv; loc = idx - CW_WV; }
    else if (idx < CW_BQ) { src = Wo; loc = idx - CW_WO; }
    else if (idx < CW_BK) { src = bq; loc = idx - CW_BQ; }
    else if (idx < CW_BV) { src = bk; loc = idx - CW_BK; }
    else if (idx < CW_BO) { src = bv; loc = idx - CW_BV; }
    else if (idx < CW_GA) { src = bo; loc = idx - CW_BO; }
    else if (idx < CW_BE) { src = ga; loc = idx - CW_GA; }
    else                  { src = be; loc = idx - CW_BE; }
    dst[idx] = src[loc];
}

// =====================================================================
// K1: fused K,V GEMMs.  32 nodes/block staged in LDS t-major; thread
// (c=tid&31, g=tid>>5) computes 4 nodes x 4 channels.  K,V -> ws (bf16).
// =====================================================================
__global__ __launch_bounds__(256) void kv_kernel(
    const float* __restrict__ physics,   // [N,10]
    const float* __restrict__ emb,       // [N,128]
    const float* __restrict__ cw,
    unsigned short* __restrict__ Kb, unsigned short* __restrict__ Vb,
    int n_nodes)
{
    __shared__ float lds[TDIM * 32];
    const int tid = threadIdx.x;
    const int nbase = blockIdx.x * 32;

    for (int idx = tid; idx < 32 * TDIM; idx += 256) {
        int m = idx / TDIM;
        int t = idx - m * TDIM;
        int node = nbase + m;
        float v = 0.f;
        if (node < n_nodes)
            v = (t < PDIM) ? physics[node * PDIM + t]
                           : emb[(size_t)node * HDIM + (t - PDIM)];
        lds[t * 32 + m] = v;
    }
    __syncthreads();

    const int c = tid & 31;
    const int g = tid >> 5;
    const float* Wk = cw + CW_WK;
    const float* Wv = cw + CW_WV;

    float ak[4][4] = {{0.f}}, av[4][4] = {{0.f}};

    for (int t = 0; t < TDIM; ++t) {
        float4 r = *(const float4*)(lds + t * 32 + 4 * g);
        float rr[4] = { r.x, r.y, r.z, r.w };
        float4 wk4 = *(const float4*)(Wk + t * HDIM + 4 * c);
        float wka[4] = { wk4.x, wk4.y, wk4.z, wk4.w };
        #pragma unroll
        for (int m = 0; m < 4; ++m) {
            #pragma unroll
            for (int j = 0; j < 4; ++j)
                ak[m][j] = fmaf(rr[m], wka[j], ak[m][j]);
        }
        if (t >= PDIM) {
            float4 wv4 = *(const float4*)(Wv + (t - PDIM) * HDIM + 4 * c);
            float wva[4] = { wv4.x, wv4.y, wv4.z, wv4.w };
            #pragma unroll
            for (int m = 0; m < 4; ++m) {
                #pragma unroll
                for (int j = 0; j < 4; ++j)
                    av[m][j] = fmaf(rr[m], wva[j], av[m][j]);
            }
        }
    }

    float4 bk4 = *(const float4*)(cw + CW_BK + 4 * c);
    float4 bv4 = *(const float4*)(cw + CW_BV + 4 * c);
    float bka[4] = { bk4.x, bk4.y, bk4.z, bk4.w };
    float bva[4] = { bv4.x, bv4.y, bv4.z, bv4.w };

    #pragma unroll
    for (int m = 0; m < 4; ++m) {
        int node = nbase + 4 * g + m;
        if (node >= n_nodes) continue;
        size_t o = (size_t)node * HDIM + 4 * c;
        store4bf(Kb + o, ak[m][0] + bka[0], ak[m][1] + bka[1], ak[m][2] + bka[2], ak[m][3] + bka[3]);
        store4bf(Vb + o, av[m][0] + bva[0], av[m][1] + bva[1], av[m][2] + bva[2], av[m][3] + bva[3]);
    }
}

// =====================================================================
// CSR build: degree -> block sums -> block-offset scan -> final scan ->
// slot fill
// =====================================================================
__global__ __launch_bounds__(256) void degree_kernel(
    const int* __restrict__ ei, int* __restrict__ deg, int n_edges, int n_nodes)
{
    int e = blockIdx.x * 256 + threadIdx.x;
    if (e < n_edges) {
        int d = ei[n_edges + e];              // row 1 = dst
        d = max(0, min(d, n_nodes - 1));
        atomicAdd(&deg[d], 1);
    }
}

__global__ __launch_bounds__(256) void scan_bsum(
    const int* __restrict__ deg, int* __restrict__ bsum, int n)
{
    __shared__ int s[256];
    int i = blockIdx.x * 256 + threadIdx.x;
    s[threadIdx.x] = (i < n) ? deg[i] : 0;
    __syncthreads();
    for (int off = 128; off > 0; off >>= 1) {
        if (threadIdx.x < off) s[threadIdx.x] += s[threadIdx.x + off];
        __syncthreads();
    }
    if (threadIdx.x == 0) bsum[blockIdx.x] = s[0];
}

__global__ __launch_bounds__(512) void scan_boff(
    const int* __restrict__ bsum, int* __restrict__ boff, int nb)
{
    __shared__ int s[512];
    int t = threadIdx.x;
    int v = (t < nb) ? bsum[t] : 0;
    s[t] = v;
    __syncthreads();
    for (int off = 1; off < 512; off <<= 1) {
        int u = (t >= off) ? s[t - off] : 0;
        __syncthreads();
        s[t] += u;
        __syncthreads();
    }
    if (t < nb) boff[t] = s[t] - v;   // exclusive
}

__global__ __launch_bounds__(256) void scan_final(
    const int* __restrict__ deg, const int* __restrict__ boff,
    int* __restrict__ row_off, int n)
{
    __shared__ int s[256];
    int t = threadIdx.x;
    int i = blockIdx.x * 256 + t;
    int v = (i < n) ? deg[i] : 0;
    s[t] = v;
    __syncthreads();
    for (int off = 1; off < 256; off <<= 1) {
        int u = (t >= off) ? s[t - off] : 0;
        __syncthreads();
        s[t] += u;
        __syncthreads();
    }
    int base = boff[blockIdx.x];
    if (i < n) row_off[i] = base + s[t] - v;
    if (i == n - 1) row_off[n] = base + s[t];
}

__global__ __launch_bounds__(256) void fill_kernel(
    const int* __restrict__ ei, const int* __restrict__ row_off,
    int* __restrict__ cursor, int* __restrict__ csr_src, int n_edges, int n_nodes)
{
    int e = blockIdx.x * 256 + threadIdx.x;
    if (e < n_edges) {
        int d = ei[n_edges + e];
        d = max(0, min(d, n_nodes - 1));
        int pos = atomicAdd(&cursor[d], 1);
        csr_src[row_off[d] + pos] = ei[e];
    }
}

// =====================================================================
// K5a: score pass.  Block = 4 dst nodes.  Q computed cooperatively in
// LDS from fp32 Wq; then one wave per node loops its edges:
// scores[i] = exp(q.k), den[node] = sum.
// =====================================================================
__global__ __launch_bounds__(256) void attn_score_kernel(
    const float* __restrict__ physics, const float* __restrict__ emb,
    const float* __restrict__ cw,
    const unsigned short* __restrict__ Kb,
    const int* __restrict__ row_off, const int* __restrict__ csr_src,
    float* __restrict__ scores, float* __restrict__ den,
    int n_nodes, int n_edges)
{
    __shared__ float fullr[4][TDIM];
    __shared__ float qs[4][HDIM];
    const int tid = threadIdx.x;
    const int nb = blockIdx.x * 4;

    for (int idx = tid; idx < 4 * TDIM; idx += 256) {
        int n = idx / TDIM, t = idx - n * TDIM;
        int node = nb + n;
        float v = 0.f;
        if (node < n_nodes)
            v = (t < PDIM) ? physics[node * PDIM + t]
                           : emb[(size_t)node * HDIM + t - PDIM];
        fullr[n][t] = v;
    }
    __syncthreads();

    const float scale = 0.088388347648318447f;   // 1/sqrt(128)
    for (int o = tid; o < 4 * HDIM; o += 256) {
        int n = o >> 7, c = o & 127;
        float acc = cw[CW_BQ + c];
        const float* w = cw + CW_WQ + c;
        for (int t = 0; t < TDIM; ++t)
            acc = fmaf(fullr[n][t], w[t * HDIM], acc);
        qs[n][c] = acc * scale;
    }
    __syncthreads();

    const int wv = tid >> 6;
    const int lane = tid & 63;
    const int wid = nb + wv;
    if (wid >= n_nodes) return;          // after all barriers

    float q0 = qs[wv][2 * lane], q1 = qs[wv][2 * lane + 1];
    int beg = row_off[wid], end = row_off[wid + 1];
    beg = max(0, min(beg, n_edges));
    end = max(beg, min(end, n_edges));
    float d = 0.f;

    for (int i = beg; i < end; ++i) {
        int s = csr_src[i];
        s = max(0, min(s, n_nodes - 1));
        unsigned kk = *(const unsigned*)(Kb + (size_t)s * HDIM + 2 * lane);
        float p = fmaf(q0, b2f_lo(kk), q1 * b2f_hi(kk));
        p += __shfl_xor(p, 1);
        p += __shfl_xor(p, 2);
        p += __shfl_xor(p, 4);
        p += __shfl_xor(p, 8);
        p += __shfl_xor(p, 16);
        p += __shfl_xor(p, 32);
        float e = __expf(fminf(p, 30.f));
        if (lane == 0) scores[i] = e;
        d += e;
    }
    if (lane == 0) den[wid] = d;
}

// =====================================================================
// K5b: aggregation pass.  One wave per dst node; writes normalized agg
// as FP32 into d_out row wid.
// =====================================================================
__global__ __launch_bounds__(256) void attn_agg_kernel(
    const unsigned short* __restrict__ Vb,
    const float* __restrict__ scores, const float* __restrict__ den,
    const int* __restrict__ row_off, const int* __restrict__ csr_src,
    float* __restrict__ agg /* = d_out, fp32 */, int n_nodes, int n_edges)
{
    const int wid = (int)((blockIdx.x * 256 + threadIdx.x) >> 6);
    const int lane = threadIdx.x & 63;
    if (wid >= n_nodes) return;

    int beg = row_off[wid], end = row_off[wid + 1];
    beg = max(0, min(beg, n_edges));
    end = max(beg, min(end, n_edges));
    float a0 = 0.f, a1 = 0.f;

    for (int i = beg; i < end; ++i) {
        int s = csr_src[i];
        s = max(0, min(s, n_nodes - 1));
        float e = scores[i];
        unsigned vv = *(const unsigned*)(Vb + (size_t)s * HDIM + 2 * lane);
        a0 = fmaf(e, b2f_lo(vv), a0);
        a1 = fmaf(e, b2f_hi(vv), a1);
    }
    float inv = 1.f / (den[wid] + 1e-8f);
    *(float2*)(agg + (size_t)wid * HDIM + 2 * lane) = make_float2(a0 * inv, a1 * inv);
}

// =====================================================================
// K6: out = agg@Wo + bo; x = emb + out; LayerNorm -> FP32 d_out in-place.
// Each block stages its 32 fp32 agg rows into LDS before overwriting.
// =====================================================================
__global__ __launch_bounds__(256) void out_ln_kernel(
    const float* __restrict__ emb,
    const float* __restrict__ cw,
    float* __restrict__ out, int n_nodes)   // out == agg (fp32)
{
    __shared__ float lds[HDIM * 32];
    const int tid = threadIdx.x;
    const int nbase = blockIdx.x * 32;

    for (int idx = tid; idx < 32 * HDIM; idx += 256) {
        int m = idx >> 7;
        int t = idx & 127;
        int node = nbase + m;
        lds[t * 32 + m] = (node < n_nodes) ? out[(size_t)node * HDIM + t] : 0.f;
    }
    __syncthreads();

    const int c = tid & 31;
    const int g = tid >> 5;
    const float* Wo = cw + CW_WO;

    float acc[4][4] = {{0.f}};
    for (int t = 0; t < HDIM; ++t) {
        float4 r = *(const float4*)(lds + t * 32 + 4 * g);
        float rr[4] = { r.x, r.y, r.z, r.w };
        float4 w4 = *(const float4*)(Wo + t * HDIM + 4 * c);
        float wa[4] = { w4.x, w4.y, w4.z, w4.w };
        #pragma unroll
        for (int m = 0; m < 4; ++m) {
            #pragma unroll
            for (int j = 0; j < 4; ++j)
                acc[m][j] = fmaf(rr[m], wa[j], acc[m][j]);
        }
    }

    float4 bo4 = *(const float4*)(cw + CW_BO + 4 * c);
    float4 ga4 = *(const float4*)(cw + CW_GA + 4 * c);
    float4 be4 = *(const float4*)(cw + CW_BE + 4 * c);
    float boa[4] = { bo4.x, bo4.y, bo4.z, bo4.w };
    float ga[4]  = { ga4.x, ga4.y, ga4.z, ga4.w };
    float ba[4]  = { be4.x, be4.y, be4.z, be4.w };

    #pragma unroll
    for (int m = 0; m < 4; ++m) {
        int node = nbase + 4 * g + m;
        float ea[4] = { 0.f, 0.f, 0.f, 0.f };
        if (node < n_nodes) {
            float4 e4 = *(const float4*)(emb + (size_t)node * HDIM + 4 * c);
            ea[0] = e4.x; ea[1] = e4.y; ea[2] = e4.z; ea[3] = e4.w;
        }

        float x[4], s1 = 0.f, s2 = 0.f;
        #pragma unroll
        for (int j = 0; j < 4; ++j) {
            x[j] = ea[j] + acc[m][j] + boa[j];
            s1 += x[j];
            s2 = fmaf(x[j], x[j], s2);
        }
        // reduce across the 32 lanes sharing this node
        #pragma unroll
        for (int mask = 1; mask <= 16; mask <<= 1) {
            s1 += __shfl_xor(s1, mask);
            s2 += __shfl_xor(s2, mask);
        }
        float mu = s1 * (1.f / 128.f);
        float var = fmaxf(s2 * (1.f / 128.f) - mu * mu, 0.f);
        float rs = rsqrtf(var + 1e-5f);
        if (node < n_nodes) {
            float4 o;
            o.x = ga[0] * (x[0] - mu) * rs + ba[0];
            o.y = ga[1] * (x[1] - mu) * rs + ba[1];
            o.z = ga[2] * (x[2] - mu) * rs + ba[2];
            o.w = ga[3] * (x[3] - mu) * rs + ba[3];
            *(float4*)(out + (size_t)node * HDIM + 4 * c) = o;
        }
    }
}

// =====================================================================
extern "C" void kernel_launch(void* const* d_in, const int* in_sizes, int n_in,
                              void* d_out, int out_size, void* d_ws, size_t ws_size,
                              hipStream_t stream)
{
    const float* physics = (const float*)d_in[0];
    const float* emb     = (const float*)d_in[1];
    const int*   ei      = (const int*)d_in[2];

    const int n_nodes = in_sizes[1] / HDIM;
    const int n_edges = in_sizes[2] / 2;
    const int NB = (n_nodes + 255) / 256;   // 391 for N=100k (<=512 req'd)

    // ws layout (~66 MB): cw + CSR + den + scores + bf16 K,V
    char* ws = (char*)d_ws;
    size_t off = 0;
    auto alloc = [&](size_t bytes) -> void* {
        void* p = ws + off;
        off = (off + bytes + 255) & ~(size_t)255;
        return p;
    };
    float* cw      = (float*)alloc((size_t)CW_TOTAL * 4);
    int* deg       = (int*)alloc((size_t)2 * n_nodes * 4);   // deg + cursor
    int* cursor    = deg + n_nodes;
    int* row_off   = (int*)alloc((size_t)(n_nodes + 1) * 4);
    int* bsum      = (int*)alloc((size_t)NB * 4);
    int* boff      = (int*)alloc((size_t)NB * 4);
    float* den     = (float*)alloc((size_t)n_nodes * 4);
    int* csr_src   = (int*)alloc((size_t)n_edges * 4);
    float* scores  = (float*)alloc((size_t)n_edges * 4);
    unsigned short* Kb = (unsigned short*)alloc((size_t)n_nodes * HDIM * 2);
    unsigned short* Vb = (unsigned short*)alloc((size_t)n_nodes * HDIM * 2);

    if (ws_size < off) {   // report bucket and bail
        int bucket = (int)min((size_t)255, ws_size >> 24);
        ws_sentinel_kernel<<<1, 64, 0, stream>>>((float*)d_out, bucket);
        return;
    }

    hipMemsetAsync(deg, 0, (size_t)2 * n_nodes * sizeof(int), stream);

    convert_weights<<<(CW_TOTAL + 255) / 256, 256, 0, stream>>>(
        (const float*)d_in[3], (const float*)d_in[5], (const float*)d_in[7],
        (const float*)d_in[9], (const float*)d_in[4], (const float*)d_in[6],
        (const float*)d_in[8], (const float*)d_in[10], (const float*)d_in[11],
        (const float*)d_in[12], cw);

    kv_kernel<<<(n_nodes + 31) / 32, 256, 0, stream>>>(
        physics, emb, cw, Kb, Vb, n_nodes);

    degree_kernel<<<(n_edges + 255) / 256, 256, 0, stream>>>(ei, deg, n_edges, n_nodes);
    scan_bsum<<<NB, 256, 0, stream>>>(deg, bsum, n_nodes);
    scan_boff<<<1, 512, 0, stream>>>(bsum, boff, NB);
    scan_final<<<NB, 256, 0, stream>>>(deg, boff, row_off, n_nodes);
    fill_kernel<<<(n_edges + 255) / 256, 256, 0, stream>>>(ei, row_off, cursor, csr_src, n_edges, n_nodes);

    attn_score_kernel<<<(n_nodes + 3) / 4, 256, 0, stream>>>(
        physics, emb, cw, Kb, row_off, csr_src, scores, den, n_nodes, n_edges);

    attn_agg_kernel<<<(n_nodes + 3) / 4, 256, 0, stream>>>(
        Vb, scores, den, row_off, csr_src, (float*)d_out, n_nodes, n_edges);

    out_ln_kernel<<<(n_nodes + 31) / 32, 256, 0, stream>>>(
        emb, cw, (float*)d_out, n_nodes);
}

// Round 7
// 790.630 us; speedup vs baseline: 1.3796x; 1.3796x over previous
//
#include <hip/hip_runtime.h>
#include <hip/hip_bf16.h>
#include <math.h>

#define PDIM 10
#define HDIM 128
#define TDIM 138   // PDIM + HDIM

// converted-weights layout (fp32, in ws)
#define CW_WQ 0
#define CW_WK 17664
#define CW_WV 35328
#define CW_WO 51712
#define CW_BQ 68096
#define CW_BK 68224
#define CW_BV 68352
#define CW_BO 68480
#define CW_GA 68608
#define CW_BE 68736
#define CW_TOTAL 68864

// ---------- bf16 helpers ----------
__device__ __forceinline__ float b2f_lo(unsigned u) { return __uint_as_float(u << 16); }
__device__ __forceinline__ float b2f_hi(unsigned u) { return __uint_as_float(u & 0xffff0000u); }
__device__ __forceinline__ unsigned short f2b(float f) {
    unsigned u = __float_as_uint(f);
    u += 0x7fffu + ((u >> 16) & 1u);
    return (unsigned short)(u >> 16);
}
__device__ __forceinline__ void store4bf(unsigned short* p, float a, float b, float c, float d) {
    ushort4 v; v.x = f2b(a); v.y = f2b(b); v.z = f2b(c); v.w = f2b(d);
    *(ushort4*)p = v;
}

__global__ void ws_sentinel_kernel(float* out, int bucket)
{
    if (threadIdx.x == 0) out[0] = ldexpf(1.f + (float)bucket / 256.f, 100);
}

// =====================================================================
// K0: gather weights/biases/gamma/beta (fp32) into one contiguous block.
// =====================================================================
__global__ __launch_bounds__(256) void convert_weights(
    const float* Wq, const float* Wk, const float* Wv, const float* Wo,
    const float* bq, const float* bk, const float* bv, const float* bo,
    const float* ga, const float* be,
    float* __restrict__ dst)
{
    int idx = blockIdx.x * 256 + threadIdx.x;
    if (idx >= CW_TOTAL) return;
    const float* src; int loc;
    if      (idx < CW_WK) { src = Wq; loc = idx - CW_WQ; }
    else if (idx < CW_WV) { src = Wk; loc = idx - CW_WK; }
    else if (idx < CW_WO) { src = Wv; loc = idx - CW_WV; }
    else if (idx < CW_BQ) { src = Wo; loc = idx - CW_WO; }
    else if (idx < CW_BK) { src = bq; loc = idx - CW_BQ; }
    else if (idx < CW_BV) { src = bk; loc = idx - CW_BK; }
    else if (idx < CW_BO) { src = bv; loc = idx - CW_BV; }
    else if (idx < CW_GA) { src = bo; loc = idx - CW_BO; }
    else if (idx < CW_BE) { src = ga; loc = idx - CW_GA; }
    else                  { src = be; loc = idx - CW_BE; }
    dst[idx] = src[loc];
}

// =====================================================================
// K1: fused Q,K,V GEMMs (Q optional via computeQ flag for the fallback
// path).  32 nodes/block staged in LDS t-major; thread (c,g) computes
// 4 nodes x 4 channels per output.  Outputs bf16.
// =====================================================================
__global__ __launch_bounds__(256) void qkv_kernel(
    const float* __restrict__ physics, const float* __restrict__ emb,
    const float* __restrict__ cw,
    unsigned short* __restrict__ Qb, unsigned short* __restrict__ Kb,
    unsigned short* __restrict__ Vb, int n_nodes, int computeQ)
{
    __shared__ float lds[TDIM * 32];
    const int tid = threadIdx.x;
    const int nbase = blockIdx.x * 32;

    for (int idx = tid; idx < 32 * TDIM; idx += 256) {
        int m = idx / TDIM;
        int t = idx - m * TDIM;
        int node = nbase + m;
        float v = 0.f;
        if (node < n_nodes)
            v = (t < PDIM) ? physics[node * PDIM + t]
                           : emb[(size_t)node * HDIM + (t - PDIM)];
        lds[t * 32 + m] = v;
    }
    __syncthreads();

    const int c = tid & 31;
    const int g = tid >> 5;
    const float* Wq = cw + CW_WQ;
    const float* Wk = cw + CW_WK;
    const float* Wv = cw + CW_WV;

    float aq[4][4] = {{0.f}}, ak[4][4] = {{0.f}}, av[4][4] = {{0.f}};

    for (int t = 0; t < TDIM; ++t) {
        float4 r = *(const float4*)(lds + t * 32 + 4 * g);
        float rr[4] = { r.x, r.y, r.z, r.w };
        float4 wk4 = *(const float4*)(Wk + t * HDIM + 4 * c);
        float wka[4] = { wk4.x, wk4.y, wk4.z, wk4.w };
        #pragma unroll
        for (int m = 0; m < 4; ++m)
            #pragma unroll
            for (int j = 0; j < 4; ++j)
                ak[m][j] = fmaf(rr[m], wka[j], ak[m][j]);
        if (computeQ) {
            float4 wq4 = *(const float4*)(Wq + t * HDIM + 4 * c);
            float wqa[4] = { wq4.x, wq4.y, wq4.z, wq4.w };
            #pragma unroll
            for (int m = 0; m < 4; ++m)
                #pragma unroll
                for (int j = 0; j < 4; ++j)
                    aq[m][j] = fmaf(rr[m], wqa[j], aq[m][j]);
        }
        if (t >= PDIM) {
            float4 wv4 = *(const float4*)(Wv + (t - PDIM) * HDIM + 4 * c);
            float wva[4] = { wv4.x, wv4.y, wv4.z, wv4.w };
            #pragma unroll
            for (int m = 0; m < 4; ++m)
                #pragma unroll
                for (int j = 0; j < 4; ++j)
                    av[m][j] = fmaf(rr[m], wva[j], av[m][j]);
        }
    }

    float4 bq4 = *(const float4*)(cw + CW_BQ + 4 * c);
    float4 bk4 = *(const float4*)(cw + CW_BK + 4 * c);
    float4 bv4 = *(const float4*)(cw + CW_BV + 4 * c);

    #pragma unroll
    for (int m = 0; m < 4; ++m) {
        int node = nbase + 4 * g + m;
        if (node >= n_nodes) continue;
        size_t o = (size_t)node * HDIM + 4 * c;
        store4bf(Kb + o, ak[m][0] + bk4.x, ak[m][1] + bk4.y, ak[m][2] + bk4.z, ak[m][3] + bk4.w);
        store4bf(Vb + o, av[m][0] + bv4.x, av[m][1] + bv4.y, av[m][2] + bv4.z, av[m][3] + bv4.w);
        if (computeQ)
            store4bf(Qb + o, aq[m][0] + bq4.x, aq[m][1] + bq4.y, aq[m][2] + bq4.z, aq[m][3] + bq4.w);
    }
}

// =====================================================================
// CSR build
// =====================================================================
__global__ __launch_bounds__(256) void degree_kernel(
    const int* __restrict__ ei, int* __restrict__ deg, int n_edges, int n_nodes)
{
    int e = blockIdx.x * 256 + threadIdx.x;
    if (e < n_edges) {
        int d = ei[n_edges + e];
        d = max(0, min(d, n_nodes - 1));
        atomicAdd(&deg[d], 1);
    }
}

__global__ __launch_bounds__(256) void scan_bsum(
    const int* __restrict__ deg, int* __restrict__ bsum, int n)
{
    __shared__ int s[256];
    int i = blockIdx.x * 256 + threadIdx.x;
    s[threadIdx.x] = (i < n) ? deg[i] : 0;
    __syncthreads();
    for (int off = 128; off > 0; off >>= 1) {
        if (threadIdx.x < off) s[threadIdx.x] += s[threadIdx.x + off];
        __syncthreads();
    }
    if (threadIdx.x == 0) bsum[blockIdx.x] = s[0];
}

__global__ __launch_bounds__(512) void scan_boff(
    const int* __restrict__ bsum, int* __restrict__ boff, int nb)
{
    __shared__ int s[512];
    int t = threadIdx.x;
    int v = (t < nb) ? bsum[t] : 0;
    s[t] = v;
    __syncthreads();
    for (int off = 1; off < 512; off <<= 1) {
        int u = (t >= off) ? s[t - off] : 0;
        __syncthreads();
        s[t] += u;
        __syncthreads();
    }
    if (t < nb) boff[t] = s[t] - v;
}

__global__ __launch_bounds__(256) void scan_final(
    const int* __restrict__ deg, const int* __restrict__ boff,
    int* __restrict__ row_off, int n)
{
    __shared__ int s[256];
    int t = threadIdx.x;
    int i = blockIdx.x * 256 + t;
    int v = (i < n) ? deg[i] : 0;
    s[t] = v;
    __syncthreads();
    for (int off = 1; off < 256; off <<= 1) {
        int u = (t >= off) ? s[t - off] : 0;
        __syncthreads();
        s[t] += u;
        __syncthreads();
    }
    int base = boff[blockIdx.x];
    if (i < n) row_off[i] = base + s[t] - v;
    if (i == n - 1) row_off[n] = base + s[t];
}

__global__ __launch_bounds__(256) void fill_kernel(
    const int* __restrict__ ei, const int* __restrict__ row_off,
    int* __restrict__ cursor, int* __restrict__ csr_src, int n_edges, int n_nodes)
{
    int e = blockIdx.x * 256 + threadIdx.x;
    if (e < n_edges) {
        int d = ei[n_edges + e];
        d = max(0, min(d, n_nodes - 1));
        int pos = atomicAdd(&cursor[d], 1);
        csr_src[row_off[d] + pos] = ei[e];
    }
}

// =====================================================================
// K5: FUSED attention.  One wave per dst node.  Lane layout:
// eg = lane>>4 (edge slot 0..3), cg = lane&15 (channels 8cg..8cg+7).
// Per 4-edge batch: uint4 K + uint4 V loads (4 edges in flight),
// 4-step shuffle dot-reduce within 16 lanes, masked exp, V accumulate.
// Final: 2-step cross-group combine; agg (fp32) -> d_out.
// =====================================================================
__global__ __launch_bounds__(256) void attn_fused_kernel(
    const unsigned short* __restrict__ Qb, const unsigned short* __restrict__ Kb,
    const unsigned short* __restrict__ Vb,
    const int* __restrict__ row_off, const int* __restrict__ csr_src,
    float* __restrict__ agg, int n_nodes, int n_edges)
{
    const int wid = (int)((blockIdx.x * 256 + threadIdx.x) >> 6);
    const int lane = threadIdx.x & 63;
    if (wid >= n_nodes) return;
    const int eg = lane >> 4;
    const int cg = lane & 15;

    const float scale = 0.088388347648318447f;   // 1/sqrt(128)
    uint4 qr = *(const uint4*)(Qb + (size_t)wid * HDIM + 8 * cg);
    float q[8];
    q[0] = b2f_lo(qr.x) * scale; q[1] = b2f_hi(qr.x) * scale;
    q[2] = b2f_lo(qr.y) * scale; q[3] = b2f_hi(qr.y) * scale;
    q[4] = b2f_lo(qr.z) * scale; q[5] = b2f_hi(qr.z) * scale;
    q[6] = b2f_lo(qr.w) * scale; q[7] = b2f_hi(qr.w) * scale;

    int beg = row_off[wid], end = row_off[wid + 1];
    beg = max(0, min(beg, n_edges));
    end = max(beg, min(end, n_edges));

    float acc[8] = {0.f,0.f,0.f,0.f,0.f,0.f,0.f,0.f};
    float den = 0.f;

    for (int i = beg; i < end; i += 4) {
        int idx = i + eg;
        bool valid = idx < end;
        int s = csr_src[valid ? idx : (end - 1)];
        s = max(0, min(s, n_nodes - 1));
        const unsigned short* krow = Kb + (size_t)s * HDIM + 8 * cg;
        const unsigned short* vrow = Vb + (size_t)s * HDIM + 8 * cg;
        uint4 kr = *(const uint4*)krow;
        uint4 vr = *(const uint4*)vrow;       // issue both loads up front

        float p;
        p = q[0] * b2f_lo(kr.x);
        p = fmaf(q[1], b2f_hi(kr.x), p);
        p = fmaf(q[2], b2f_lo(kr.y), p);
        p = fmaf(q[3], b2f_hi(kr.y), p);
        p = fmaf(q[4], b2f_lo(kr.z), p);
        p = fmaf(q[5], b2f_hi(kr.z), p);
        p = fmaf(q[6], b2f_lo(kr.w), p);
        p = fmaf(q[7], b2f_hi(kr.w), p);
        p += __shfl_xor(p, 1);
        p += __shfl_xor(p, 2);
        p += __shfl_xor(p, 4);
        p += __shfl_xor(p, 8);

        float e = valid ? __expf(fminf(p, 60.f)) : 0.f;
        den += e;
        acc[0] = fmaf(e, b2f_lo(vr.x), acc[0]);
        acc[1] = fmaf(e, b2f_hi(vr.x), acc[1]);
        acc[2] = fmaf(e, b2f_lo(vr.y), acc[2]);
        acc[3] = fmaf(e, b2f_hi(vr.y), acc[3]);
        acc[4] = fmaf(e, b2f_lo(vr.z), acc[4]);
        acc[5] = fmaf(e, b2f_hi(vr.z), acc[5]);
        acc[6] = fmaf(e, b2f_lo(vr.w), acc[6]);
        acc[7] = fmaf(e, b2f_hi(vr.w), acc[7]);
    }

    // combine the 4 edge-groups (lanes with equal cg)
    #pragma unroll
    for (int j = 0; j < 8; ++j) {
        acc[j] += __shfl_xor(acc[j], 16);
        acc[j] += __shfl_xor(acc[j], 32);
    }
    den += __shfl_xor(den, 16);
    den += __shfl_xor(den, 32);

    float inv = 1.f / (den + 1e-8f);
    if (eg == 0) {
        float* dst = agg + (size_t)wid * HDIM + 8 * cg;
        *(float4*)dst       = make_float4(acc[0]*inv, acc[1]*inv, acc[2]*inv, acc[3]*inv);
        *(float4*)(dst + 4) = make_float4(acc[4]*inv, acc[5]*inv, acc[6]*inv, acc[7]*inv);
    }
}

// =====================================================================
// Fallback split kernels (proven R6 path) — used only if ws too small.
// =====================================================================
__global__ __launch_bounds__(256) void attn_score_kernel(
    const float* __restrict__ physics, const float* __restrict__ emb,
    const float* __restrict__ cw,
    const unsigned short* __restrict__ Kb,
    const int* __restrict__ row_off, const int* __restrict__ csr_src,
    float* __restrict__ scores, float* __restrict__ den,
    int n_nodes, int n_edges)
{
    __shared__ float fullr[4][TDIM];
    __shared__ float qs[4][HDIM];
    const int tid = threadIdx.x;
    const int nb = blockIdx.x * 4;

    for (int idx = tid; idx < 4 * TDIM; idx += 256) {
        int n = idx / TDIM, t = idx - n * TDIM;
        int node = nb + n;
        float v = 0.f;
        if (node < n_nodes)
            v = (t < PDIM) ? physics[node * PDIM + t]
                           : emb[(size_t)node * HDIM + t - PDIM];
        fullr[n][t] = v;
    }
    __syncthreads();

    const float scale = 0.088388347648318447f;
    for (int o = tid; o < 4 * HDIM; o += 256) {
        int n = o >> 7, c = o & 127;
        float acc = cw[CW_BQ + c];
        const float* w = cw + CW_WQ + c;
        for (int t = 0; t < TDIM; ++t)
            acc = fmaf(fullr[n][t], w[t * HDIM], acc);
        qs[n][c] = acc * scale;
    }
    __syncthreads();

    const int wv = tid >> 6;
    const int lane = tid & 63;
    const int wid = nb + wv;
    if (wid >= n_nodes) return;

    float q0 = qs[wv][2 * lane], q1 = qs[wv][2 * lane + 1];
    int beg = row_off[wid], end = row_off[wid + 1];
    beg = max(0, min(beg, n_edges));
    end = max(beg, min(end, n_edges));
    float d = 0.f;

    for (int i = beg; i < end; ++i) {
        int s = csr_src[i];
        s = max(0, min(s, n_nodes - 1));
        unsigned kk = *(const unsigned*)(Kb + (size_t)s * HDIM + 2 * lane);
        float p = fmaf(q0, b2f_lo(kk), q1 * b2f_hi(kk));
        p += __shfl_xor(p, 1);
        p += __shfl_xor(p, 2);
        p += __shfl_xor(p, 4);
        p += __shfl_xor(p, 8);
        p += __shfl_xor(p, 16);
        p += __shfl_xor(p, 32);
        float e = __expf(fminf(p, 30.f));
        if (lane == 0) scores[i] = e;
        d += e;
    }
    if (lane == 0) den[wid] = d;
}

__global__ __launch_bounds__(256) void attn_agg_kernel(
    const unsigned short* __restrict__ Vb,
    const float* __restrict__ scores, const float* __restrict__ den,
    const int* __restrict__ row_off, const int* __restrict__ csr_src,
    float* __restrict__ agg, int n_nodes, int n_edges)
{
    const int wid = (int)((blockIdx.x * 256 + threadIdx.x) >> 6);
    const int lane = threadIdx.x & 63;
    if (wid >= n_nodes) return;

    int beg = row_off[wid], end = row_off[wid + 1];
    beg = max(0, min(beg, n_edges));
    end = max(beg, min(end, n_edges));
    float a0 = 0.f, a1 = 0.f;

    for (int i = beg; i < end; ++i) {
        int s = csr_src[i];
        s = max(0, min(s, n_nodes - 1));
        float e = scores[i];
        unsigned vv = *(const unsigned*)(Vb + (size_t)s * HDIM + 2 * lane);
        a0 = fmaf(e, b2f_lo(vv), a0);
        a1 = fmaf(e, b2f_hi(vv), a1);
    }
    float inv = 1.f / (den[wid] + 1e-8f);
    *(float2*)(agg + (size_t)wid * HDIM + 2 * lane) = make_float2(a0 * inv, a1 * inv);
}

// =====================================================================
// K6: out = agg@Wo + bo; x = emb + out; LayerNorm -> FP32 d_out in-place.
// =====================================================================
__global__ __launch_bounds__(256) void out_ln_kernel(
    const float* __restrict__ emb,
    const float* __restrict__ cw,
    float* __restrict__ out, int n_nodes)
{
    __shared__ float lds[HDIM * 32];
    const int tid = threadIdx.x;
    const int nbase = blockIdx.x * 32;

    for (int idx = tid; idx < 32 * HDIM; idx += 256) {
        int m = idx >> 7;
        int t = idx & 127;
        int node = nbase + m;
        lds[t * 32 + m] = (node < n_nodes) ? out[(size_t)node * HDIM + t] : 0.f;
    }
    __syncthreads();

    const int c = tid & 31;
    const int g = tid >> 5;
    const float* Wo = cw + CW_WO;

    float acc[4][4] = {{0.f}};
    for (int t = 0; t < HDIM; ++t) {
        float4 r = *(const float4*)(lds + t * 32 + 4 * g);
        float rr[4] = { r.x, r.y, r.z, r.w };
        float4 w4 = *(const float4*)(Wo + t * HDIM + 4 * c);
        float wa[4] = { w4.x, w4.y, w4.z, w4.w };
        #pragma unroll
        for (int m = 0; m < 4; ++m)
            #pragma unroll
            for (int j = 0; j < 4; ++j)
                acc[m][j] = fmaf(rr[m], wa[j], acc[m][j]);
    }

    float4 bo4 = *(const float4*)(cw + CW_BO + 4 * c);
    float4 ga4 = *(const float4*)(cw + CW_GA + 4 * c);
    float4 be4 = *(const float4*)(cw + CW_BE + 4 * c);
    float boa[4] = { bo4.x, bo4.y, bo4.z, bo4.w };
    float ga[4]  = { ga4.x, ga4.y, ga4.z, ga4.w };
    float ba[4]  = { be4.x, be4.y, be4.z, be4.w };

    #pragma unroll
    for (int m = 0; m < 4; ++m) {
        int node = nbase + 4 * g + m;
        float ea[4] = { 0.f, 0.f, 0.f, 0.f };
        if (node < n_nodes) {
            float4 e4 = *(const float4*)(emb + (size_t)node * HDIM + 4 * c);
            ea[0] = e4.x; ea[1] = e4.y; ea[2] = e4.z; ea[3] = e4.w;
        }

        float x[4], s1 = 0.f, s2 = 0.f;
        #pragma unroll
        for (int j = 0; j < 4; ++j) {
            x[j] = ea[j] + acc[m][j] + boa[j];
            s1 += x[j];
            s2 = fmaf(x[j], x[j], s2);
        }
        #pragma unroll
        for (int mask = 1; mask <= 16; mask <<= 1) {
            s1 += __shfl_xor(s1, mask);
            s2 += __shfl_xor(s2, mask);
        }
        float mu = s1 * (1.f / 128.f);
        float var = fmaxf(s2 * (1.f / 128.f) - mu * mu, 0.f);
        float rs = rsqrtf(var + 1e-5f);
        if (node < n_nodes) {
            float4 o;
            o.x = ga[0] * (x[0] - mu) * rs + ba[0];
            o.y = ga[1] * (x[1] - mu) * rs + ba[1];
            o.z = ga[2] * (x[2] - mu) * rs + ba[2];
            o.w = ga[3] * (x[3] - mu) * rs + ba[3];
            *(float4*)(out + (size_t)node * HDIM + 4 * c) = o;
        }
    }
}

// =====================================================================
extern "C" void kernel_launch(void* const* d_in, const int* in_sizes, int n_in,
                              void* d_out, int out_size, void* d_ws, size_t ws_size,
                              hipStream_t stream)
{
    const float* physics = (const float*)d_in[0];
    const float* emb     = (const float*)d_in[1];
    const int*   ei      = (const int*)d_in[2];

    const int n_nodes = in_sizes[1] / HDIM;
    const int n_edges = in_sizes[2] / 2;
    const int NB = (n_nodes + 255) / 256;

    char* ws = (char*)d_ws;
    size_t off = 0;
    auto alloc = [&](size_t bytes) -> void* {
        void* p = ws + off;
        off = (off + bytes + 255) & ~(size_t)255;
        return p;
    };

    // common buffers
    float* cw      = (float*)alloc((size_t)CW_TOTAL * 4);
    int* deg       = (int*)alloc((size_t)2 * n_nodes * 4);   // deg + cursor
    int* cursor    = deg + n_nodes;
    int* row_off   = (int*)alloc((size_t)(n_nodes + 1) * 4);
    int* bsum      = (int*)alloc((size_t)NB * 4);
    int* boff      = (int*)alloc((size_t)NB * 4);
    int* csr_src   = (int*)alloc((size_t)n_edges * 4);
    unsigned short* Kb = (unsigned short*)alloc((size_t)n_nodes * HDIM * 2);
    unsigned short* Vb = (unsigned short*)alloc((size_t)n_nodes * HDIM * 2);
    size_t common_off = off;

    // fused path extra: Q buffer (25.6 MB)
    unsigned short* Qb = (unsigned short*)alloc((size_t)n_nodes * HDIM * 2);
    size_t fused_need = off;

    // fallback path extra (overlays Qb space): scores + den
    bool fused = (ws_size >= fused_need);
    float* scores = nullptr; float* den = nullptr;
    if (!fused) {
        off = common_off;
        scores = (float*)alloc((size_t)n_edges * 4);
        den    = (float*)alloc((size_t)n_nodes * 4);
        if (ws_size < off) {
            int bucket = (int)min((size_t)255, ws_size >> 24);
            ws_sentinel_kernel<<<1, 64, 0, stream>>>((float*)d_out, bucket);
            return;
        }
    }

    hipMemsetAsync(deg, 0, (size_t)2 * n_nodes * sizeof(int), stream);

    convert_weights<<<(CW_TOTAL + 255) / 256, 256, 0, stream>>>(
        (const float*)d_in[3], (const float*)d_in[5], (const float*)d_in[7],
        (const float*)d_in[9], (const float*)d_in[4], (const float*)d_in[6],
        (const float*)d_in[8], (const float*)d_in[10], (const float*)d_in[11],
        (const float*)d_in[12], cw);

    qkv_kernel<<<(n_nodes + 31) / 32, 256, 0, stream>>>(
        physics, emb, cw, fused ? Qb : Kb /*unused*/, Kb, Vb, n_nodes, fused ? 1 : 0);

    degree_kernel<<<(n_edges + 255) / 256, 256, 0, stream>>>(ei, deg, n_edges, n_nodes);
    scan_bsum<<<NB, 256, 0, stream>>>(deg, bsum, n_nodes);
    scan_boff<<<1, 512, 0, stream>>>(bsum, boff, NB);
    scan_final<<<NB, 256, 0, stream>>>(deg, boff, row_off, n_nodes);
    fill_kernel<<<(n_edges + 255) / 256, 256, 0, stream>>>(ei, row_off, cursor, csr_src, n_edges, n_nodes);

    if (fused) {
        attn_fused_kernel<<<(n_nodes + 3) / 4, 256, 0, stream>>>(
            Qb, Kb, Vb, row_off, csr_src, (float*)d_out, n_nodes, n_edges);
    } else {
        attn_score_kernel<<<(n_nodes + 3) / 4, 256, 0, stream>>>(
            physics, emb, cw, Kb, row_off, csr_src, scores, den, n_nodes, n_edges);
        attn_agg_kernel<<<(n_nodes + 3) / 4, 256, 0, stream>>>(
            Vb, scores, den, row_off, csr_src, (float*)d_out, n_nodes, n_edges);
    }

    out_ln_kernel<<<(n_nodes + 31) / 32, 256, 0, stream>>>(
        emb, cw, (float*)d_out, n_nodes);
}

// Round 8
// 647.578 us; speedup vs baseline: 1.6844x; 1.2209x over previous
//
#include <hip/hip_runtime.h>
#include <hip/hip_bf16.h>
#include <math.h>

#define PDIM 10
#define HDIM 128
#define TDIM 138   // PDIM + HDIM
#define KPAD 160   // 5 chunks of 32
#define AROW 168   // LDS A-row stride in bf16 (conflict-mitigating pad)

// converted-weights layout (fp32, in ws)
#define CW_WQ 0
#define CW_WK 17664
#define CW_WV 35328
#define CW_WO 51712
#define CW_BQ 68096
#define CW_BK 68224
#define CW_BV 68352
#define CW_BO 68480
#define CW_GA 68608
#define CW_BE 68736
#define CW_TOTAL 68864

typedef short v8s __attribute__((ext_vector_type(8)));   // 8 bf16
typedef float v4f __attribute__((ext_vector_type(4)));   // MFMA acc

// ---------- bf16 helpers ----------
__device__ __forceinline__ float b2f_lo(unsigned u) { return __uint_as_float(u << 16); }
__device__ __forceinline__ float b2f_hi(unsigned u) { return __uint_as_float(u & 0xffff0000u); }
__device__ __forceinline__ unsigned short f2b(float f) {
    unsigned u = __float_as_uint(f);
    u += 0x7fffu + ((u >> 16) & 1u);
    return (unsigned short)(u >> 16);
}
__device__ __forceinline__ void store4bf(unsigned short* p, float a, float b, float c, float d) {
    ushort4 v; v.x = f2b(a); v.y = f2b(b); v.z = f2b(c); v.w = f2b(d);
    *(ushort4*)p = v;
}

__global__ void ws_sentinel_kernel(float* out, int bucket)
{
    if (threadIdx.x == 0) out[0] = ldexpf(1.f + (float)bucket / 256.f, 100);
}

// =====================================================================
// K0: gather weights/biases/gamma/beta (fp32) into one contiguous block.
// =====================================================================
__global__ __launch_bounds__(256) void convert_weights(
    const float* Wq, const float* Wk, const float* Wv, const float* Wo,
    const float* bq, const float* bk, const float* bv, const float* bo,
    const float* ga, const float* be,
    float* __restrict__ dst)
{
    int idx = blockIdx.x * 256 + threadIdx.x;
    if (idx >= CW_TOTAL) return;
    const float* src; int loc;
    if      (idx < CW_WK) { src = Wq; loc = idx - CW_WQ; }
    else if (idx < CW_WV) { src = Wk; loc = idx - CW_WK; }
    else if (idx < CW_WO) { src = Wv; loc = idx - CW_WV; }
    else if (idx < CW_BQ) { src = Wo; loc = idx - CW_WO; }
    else if (idx < CW_BK) { src = bq; loc = idx - CW_BQ; }
    else if (idx < CW_BV) { src = bk; loc = idx - CW_BK; }
    else if (idx < CW_BO) { src = bv; loc = idx - CW_BV; }
    else if (idx < CW_GA) { src = bo; loc = idx - CW_BO; }
    else if (idx < CW_BE) { src = ga; loc = idx - CW_GA; }
    else                  { src = be; loc = idx - CW_BE; }
    dst[idx] = src[loc];
}

// =====================================================================
// K0c: pack Wq/Wk/Wv' into MFMA B-fragment-major bf16:
// wfrag[mat][kc][nt][lane][j]  (j: 8 bf16 = 16 B per lane, coalesced).
// B-element (k = kc*32 + (lane>>4)*8 + j, n = nt*16 + (lane&15)).
// For V the effective weight is shifted: rows k<PDIM are zero.
// =====================================================================
__global__ __launch_bounds__(256) void pack_wfrag(
    const float* __restrict__ cw, unsigned short* __restrict__ wfrag)
{
    int g = blockIdx.x * 256 + threadIdx.x;
    if (g >= 3 * 5 * 8 * 64) return;
    int lane = g & 63;
    int nt   = (g >> 6) & 7;
    int mk   = g >> 9;            // mat*5 + kc
    int kc = mk % 5, mat = mk / 5;
    int quad = lane >> 4, l15 = lane & 15;
    int n = nt * 16 + l15;

    unsigned short* dst = wfrag + (size_t)g * 8;
    #pragma unroll
    for (int j = 0; j < 8; ++j) {
        int k = kc * 32 + quad * 8 + j;
        float v = 0.f;
        if (mat == 0)      { if (k < TDIM) v = cw[CW_WQ + k * HDIM + n]; }
        else if (mat == 1) { if (k < TDIM) v = cw[CW_WK + k * HDIM + n]; }
        else               { if (k >= PDIM && k < TDIM) v = cw[CW_WV + (k - PDIM) * HDIM + n]; }
        dst[j] = f2b(v);
    }
}

// =====================================================================
// K1-MFMA: fused Q,K,V GEMMs on matrix cores.
// Block = 256 threads = 4 waves; tile = 64 nodes x 128 cols, K=160.
// Wave w computes rows 16w..16w+15 via 16x16x32 bf16 MFMA:
//   A frag: m=lane&15, k=quad*8+j (from LDS bf16, row stride 168)
//   B frag: n=lane&15, k=quad*8+j (from wfrag, 16B coalesced)
//   D:      col=lane&15, row=quad*4+reg   [doc-verified m89/m91]
// Epilogue: transpose D through LDS (fp32, stride 132), +bias, bf16 out.
// =====================================================================
__global__ __launch_bounds__(256) void qkv_mfma_kernel(
    const float* __restrict__ physics, const float* __restrict__ emb,
    const float* __restrict__ cw, const unsigned short* __restrict__ wfrag,
    unsigned short* __restrict__ Qb, unsigned short* __restrict__ Kb,
    unsigned short* __restrict__ Vb, int n_nodes)
{
    __shared__ __align__(16) float tlds[64 * 132];     // 33792 B (union)
    unsigned short* lds16 = (unsigned short*)tlds;     // A tile: 64 x 168 bf16

    const int tid = threadIdx.x;
    const int nbase = blockIdx.x * 64;
    const int lane = tid & 63;
    const int w = tid >> 6;
    const int quad = lane >> 4;
    const int l15 = lane & 15;

    // ---- stage A (fp32 -> bf16 pairs), zero-pad k>=138 and rows >= n ----
    for (int idx = tid; idx < 64 * 84; idx += 256) {
        int r = idx / 84, p = idx - r * 84;     // pair p covers k=2p,2p+1
        int node = nbase + r;
        float v0 = 0.f, v1 = 0.f;
        if (node < n_nodes) {
            int k = 2 * p;
            if (k + 1 < PDIM) {
                const float* ph = physics + node * PDIM + k;
                v0 = ph[0]; v1 = ph[1];
            } else if (k < TDIM) {
                const float* em = emb + (size_t)node * HDIM + (k - PDIM);
                v0 = em[0]; v1 = em[1];
            }
        }
        ((unsigned*)lds16)[r * 84 + p] = (unsigned)f2b(v0) | ((unsigned)f2b(v1) << 16);
    }
    __syncthreads();

    v4f acc[3][8];
    #pragma unroll
    for (int mat = 0; mat < 3; ++mat)
        #pragma unroll
        for (int nt = 0; nt < 8; ++nt)
            acc[mat][nt] = (v4f){0.f, 0.f, 0.f, 0.f};

    for (int kc = 0; kc < 5; ++kc) {
        v8s a = *(v8s*)(lds16 + (w * 16 + l15) * AROW + kc * 32 + quad * 8);
        #pragma unroll
        for (int mat = 0; mat < 3; ++mat) {
            #pragma unroll
            for (int nt = 0; nt < 8; ++nt) {
                v8s b = *(const v8s*)(wfrag +
                    ((size_t)(((mat * 5 + kc) * 8 + nt) * 64 + lane)) * 8);
                acc[mat][nt] = __builtin_amdgcn_mfma_f32_16x16x32_bf16(
                    a, b, acc[mat][nt], 0, 0, 0);
            }
        }
    }
    __syncthreads();   // A-tile reads done; LDS reused for transpose

    // ---- epilogue: per matrix, D -> LDS -> bias -> bf16 global ----
    const int r = tid >> 2;
    const int cseg = (tid & 3) * 32;
    const int node = nbase + r;

    for (int mat = 0; mat < 3; ++mat) {
        #pragma unroll
        for (int nt = 0; nt < 8; ++nt)
            #pragma unroll
            for (int reg = 0; reg < 4; ++reg)
                tlds[(w * 16 + quad * 4 + reg) * 132 + nt * 16 + l15] = acc[mat][nt][reg];
        __syncthreads();

        if (node < n_nodes) {
            unsigned short* dst = (mat == 0 ? Qb : (mat == 1 ? Kb : Vb))
                                  + (size_t)node * HDIM + cseg;
            const float* brow = cw + CW_BQ + mat * HDIM + cseg;
            #pragma unroll
            for (int j = 0; j < 8; ++j) {
                float4 v = *(float4*)&tlds[r * 132 + cseg + 4 * j];
                float4 b = *(const float4*)(brow + 4 * j);
                store4bf(dst + 4 * j, v.x + b.x, v.y + b.y, v.z + b.z, v.w + b.w);
            }
        }
        __syncthreads();
    }
}

// =====================================================================
// K1 fallback (VALU QKV, proven R6/R7 path)
// =====================================================================
__global__ __launch_bounds__(256) void qkv_kernel(
    const float* __restrict__ physics, const float* __restrict__ emb,
    const float* __restrict__ cw,
    unsigned short* __restrict__ Qb, unsigned short* __restrict__ Kb,
    unsigned short* __restrict__ Vb, int n_nodes, int computeQ)
{
    __shared__ float lds[TDIM * 32];
    const int tid = threadIdx.x;
    const int nbase = blockIdx.x * 32;

    for (int idx = tid; idx < 32 * TDIM; idx += 256) {
        int m = idx / TDIM;
        int t = idx - m * TDIM;
        int node = nbase + m;
        float v = 0.f;
        if (node < n_nodes)
            v = (t < PDIM) ? physics[node * PDIM + t]
                           : emb[(size_t)node * HDIM + (t - PDIM)];
        lds[t * 32 + m] = v;
    }
    __syncthreads();

    const int c = tid & 31;
    const int g = tid >> 5;
    const float* Wq = cw + CW_WQ;
    const float* Wk = cw + CW_WK;
    const float* Wv = cw + CW_WV;

    float aq[4][4] = {{0.f}}, ak[4][4] = {{0.f}}, av[4][4] = {{0.f}};

    for (int t = 0; t < TDIM; ++t) {
        float4 r = *(const float4*)(lds + t * 32 + 4 * g);
        float rr[4] = { r.x, r.y, r.z, r.w };
        float4 wk4 = *(const float4*)(Wk + t * HDIM + 4 * c);
        float wka[4] = { wk4.x, wk4.y, wk4.z, wk4.w };
        #pragma unroll
        for (int m = 0; m < 4; ++m)
            #pragma unroll
            for (int j = 0; j < 4; ++j)
                ak[m][j] = fmaf(rr[m], wka[j], ak[m][j]);
        if (computeQ) {
            float4 wq4 = *(const float4*)(Wq + t * HDIM + 4 * c);
            float wqa[4] = { wq4.x, wq4.y, wq4.z, wq4.w };
            #pragma unroll
            for (int m = 0; m < 4; ++m)
                #pragma unroll
                for (int j = 0; j < 4; ++j)
                    aq[m][j] = fmaf(rr[m], wqa[j], aq[m][j]);
        }
        if (t >= PDIM) {
            float4 wv4 = *(const float4*)(Wv + (t - PDIM) * HDIM + 4 * c);
            float wva[4] = { wv4.x, wv4.y, wv4.z, wv4.w };
            #pragma unroll
            for (int m = 0; m < 4; ++m)
                #pragma unroll
                for (int j = 0; j < 4; ++j)
                    av[m][j] = fmaf(rr[m], wva[j], av[m][j]);
        }
    }

    float4 bq4 = *(const float4*)(cw + CW_BQ + 4 * c);
    float4 bk4 = *(const float4*)(cw + CW_BK + 4 * c);
    float4 bv4 = *(const float4*)(cw + CW_BV + 4 * c);

    #pragma unroll
    for (int m = 0; m < 4; ++m) {
        int node = nbase + 4 * g + m;
        if (node >= n_nodes) continue;
        size_t o = (size_t)node * HDIM + 4 * c;
        store4bf(Kb + o, ak[m][0] + bk4.x, ak[m][1] + bk4.y, ak[m][2] + bk4.z, ak[m][3] + bk4.w);
        store4bf(Vb + o, av[m][0] + bv4.x, av[m][1] + bv4.y, av[m][2] + bv4.z, av[m][3] + bv4.w);
        if (computeQ)
            store4bf(Qb + o, aq[m][0] + bq4.x, aq[m][1] + bq4.y, aq[m][2] + bq4.z, aq[m][3] + bq4.w);
    }
}

// =====================================================================
// CSR build
// =====================================================================
__global__ __launch_bounds__(256) void degree_kernel(
    const int* __restrict__ ei, int* __restrict__ deg, int n_edges, int n_nodes)
{
    int e = blockIdx.x * 256 + threadIdx.x;
    if (e < n_edges) {
        int d = ei[n_edges + e];
        d = max(0, min(d, n_nodes - 1));
        atomicAdd(&deg[d], 1);
    }
}

__global__ __launch_bounds__(256) void scan_bsum(
    const int* __restrict__ deg, int* __restrict__ bsum, int n)
{
    __shared__ int s[256];
    int i = blockIdx.x * 256 + threadIdx.x;
    s[threadIdx.x] = (i < n) ? deg[i] : 0;
    __syncthreads();
    for (int off = 128; off > 0; off >>= 1) {
        if (threadIdx.x < off) s[threadIdx.x] += s[threadIdx.x + off];
        __syncthreads();
    }
    if (threadIdx.x == 0) bsum[blockIdx.x] = s[0];
}

__global__ __launch_bounds__(512) void scan_boff(
    const int* __restrict__ bsum, int* __restrict__ boff, int nb)
{
    __shared__ int s[512];
    int t = threadIdx.x;
    int v = (t < nb) ? bsum[t] : 0;
    s[t] = v;
    __syncthreads();
    for (int off = 1; off < 512; off <<= 1) {
        int u = (t >= off) ? s[t - off] : 0;
        __syncthreads();
        s[t] += u;
        __syncthreads();
    }
    if (t < nb) boff[t] = s[t] - v;
}

__global__ __launch_bounds__(256) void scan_final(
    const int* __restrict__ deg, const int* __restrict__ boff,
    int* __restrict__ row_off, int n)
{
    __shared__ int s[256];
    int t = threadIdx.x;
    int i = blockIdx.x * 256 + t;
    int v = (i < n) ? deg[i] : 0;
    s[t] = v;
    __syncthreads();
    for (int off = 1; off < 256; off <<= 1) {
        int u = (t >= off) ? s[t - off] : 0;
        __syncthreads();
        s[t] += u;
        __syncthreads();
    }
    int base = boff[blockIdx.x];
    if (i < n) row_off[i] = base + s[t] - v;
    if (i == n - 1) row_off[n] = base + s[t];
}

__global__ __launch_bounds__(256) void fill_kernel(
    const int* __restrict__ ei, const int* __restrict__ row_off,
    int* __restrict__ cursor, int* __restrict__ csr_src, int n_edges, int n_nodes)
{
    int e = blockIdx.x * 256 + threadIdx.x;
    if (e < n_edges) {
        int d = ei[n_edges + e];
        d = max(0, min(d, n_nodes - 1));
        int pos = atomicAdd(&cursor[d], 1);
        csr_src[row_off[d] + pos] = ei[e];
    }
}

// =====================================================================
// K5: FUSED attention (R7, unchanged).  One wave per dst node;
// eg = lane>>4 edge slot, cg = lane&15 channel group (8 ch).
// =====================================================================
__global__ __launch_bounds__(256) void attn_fused_kernel(
    const unsigned short* __restrict__ Qb, const unsigned short* __restrict__ Kb,
    const unsigned short* __restrict__ Vb,
    const int* __restrict__ row_off, const int* __restrict__ csr_src,
    float* __restrict__ agg, int n_nodes, int n_edges)
{
    const int wid = (int)((blockIdx.x * 256 + threadIdx.x) >> 6);
    const int lane = threadIdx.x & 63;
    if (wid >= n_nodes) return;
    const int eg = lane >> 4;
    const int cg = lane & 15;

    const float scale = 0.088388347648318447f;   // 1/sqrt(128)
    uint4 qr = *(const uint4*)(Qb + (size_t)wid * HDIM + 8 * cg);
    float q[8];
    q[0] = b2f_lo(qr.x) * scale; q[1] = b2f_hi(qr.x) * scale;
    q[2] = b2f_lo(qr.y) * scale; q[3] = b2f_hi(qr.y) * scale;
    q[4] = b2f_lo(qr.z) * scale; q[5] = b2f_hi(qr.z) * scale;
    q[6] = b2f_lo(qr.w) * scale; q[7] = b2f_hi(qr.w) * scale;

    int beg = row_off[wid], end = row_off[wid + 1];
    beg = max(0, min(beg, n_edges));
    end = max(beg, min(end, n_edges));

    float acc[8] = {0.f,0.f,0.f,0.f,0.f,0.f,0.f,0.f};
    float den = 0.f;

    for (int i = beg; i < end; i += 4) {
        int idx = i + eg;
        bool valid = idx < end;
        int s = csr_src[valid ? idx : (end - 1)];
        s = max(0, min(s, n_nodes - 1));
        uint4 kr = *(const uint4*)(Kb + (size_t)s * HDIM + 8 * cg);
        uint4 vr = *(const uint4*)(Vb + (size_t)s * HDIM + 8 * cg);

        float p;
        p = q[0] * b2f_lo(kr.x);
        p = fmaf(q[1], b2f_hi(kr.x), p);
        p = fmaf(q[2], b2f_lo(kr.y), p);
        p = fmaf(q[3], b2f_hi(kr.y), p);
        p = fmaf(q[4], b2f_lo(kr.z), p);
        p = fmaf(q[5], b2f_hi(kr.z), p);
        p = fmaf(q[6], b2f_lo(kr.w), p);
        p = fmaf(q[7], b2f_hi(kr.w), p);
        p += __shfl_xor(p, 1);
        p += __shfl_xor(p, 2);
        p += __shfl_xor(p, 4);
        p += __shfl_xor(p, 8);

        float e = valid ? __expf(fminf(p, 60.f)) : 0.f;
        den += e;
        acc[0] = fmaf(e, b2f_lo(vr.x), acc[0]);
        acc[1] = fmaf(e, b2f_hi(vr.x), acc[1]);
        acc[2] = fmaf(e, b2f_lo(vr.y), acc[2]);
        acc[3] = fmaf(e, b2f_hi(vr.y), acc[3]);
        acc[4] = fmaf(e, b2f_lo(vr.z), acc[4]);
        acc[5] = fmaf(e, b2f_hi(vr.z), acc[5]);
        acc[6] = fmaf(e, b2f_lo(vr.w), acc[6]);
        acc[7] = fmaf(e, b2f_hi(vr.w), acc[7]);
    }

    #pragma unroll
    for (int j = 0; j < 8; ++j) {
        acc[j] += __shfl_xor(acc[j], 16);
        acc[j] += __shfl_xor(acc[j], 32);
    }
    den += __shfl_xor(den, 16);
    den += __shfl_xor(den, 32);

    float inv = 1.f / (den + 1e-8f);
    if (eg == 0) {
        float* dst = agg + (size_t)wid * HDIM + 8 * cg;
        *(float4*)dst       = make_float4(acc[0]*inv, acc[1]*inv, acc[2]*inv, acc[3]*inv);
        *(float4*)(dst + 4) = make_float4(acc[4]*inv, acc[5]*inv, acc[6]*inv, acc[7]*inv);
    }
}

// =====================================================================
// Fallback split attention (R6 path)
// =====================================================================
__global__ __launch_bounds__(256) void attn_score_kernel(
    const float* __restrict__ physics, const float* __restrict__ emb,
    const float* __restrict__ cw,
    const unsigned short* __restrict__ Kb,
    const int* __restrict__ row_off, const int* __restrict__ csr_src,
    float* __restrict__ scores, float* __restrict__ den,
    int n_nodes, int n_edges)
{
    __shared__ float fullr[4][TDIM];
    __shared__ float qs[4][HDIM];
    const int tid = threadIdx.x;
    const int nb = blockIdx.x * 4;

    for (int idx = tid; idx < 4 * TDIM; idx += 256) {
        int n = idx / TDIM, t = idx - n * TDIM;
        int node = nb + n;
        float v = 0.f;
        if (node < n_nodes)
            v = (t < PDIM) ? physics[node * PDIM + t]
                           : emb[(size_t)node * HDIM + t - PDIM];
        fullr[n][t] = v;
    }
    __syncthreads();

    const float scale = 0.088388347648318447f;
    for (int o = tid; o < 4 * HDIM; o += 256) {
        int n = o >> 7, c = o & 127;
        float acc = cw[CW_BQ + c];
        const float* w = cw + CW_WQ + c;
        for (int t = 0; t < TDIM; ++t)
            acc = fmaf(fullr[n][t], w[t * HDIM], acc);
        qs[n][c] = acc * scale;
    }
    __syncthreads();

    const int wv = tid >> 6;
    const int lane = tid & 63;
    const int wid = nb + wv;
    if (wid >= n_nodes) return;

    float q0 = qs[wv][2 * lane], q1 = qs[wv][2 * lane + 1];
    int beg = row_off[wid], end = row_off[wid + 1];
    beg = max(0, min(beg, n_edges));
    end = max(beg, min(end, n_edges));
    float d = 0.f;

    for (int i = beg; i < end; ++i) {
        int s = csr_src[i];
        s = max(0, min(s, n_nodes - 1));
        unsigned kk = *(const unsigned*)(Kb + (size_t)s * HDIM + 2 * lane);
        float p = fmaf(q0, b2f_lo(kk), q1 * b2f_hi(kk));
        p += __shfl_xor(p, 1);
        p += __shfl_xor(p, 2);
        p += __shfl_xor(p, 4);
        p += __shfl_xor(p, 8);
        p += __shfl_xor(p, 16);
        p += __shfl_xor(p, 32);
        float e = __expf(fminf(p, 30.f));
        if (lane == 0) scores[i] = e;
        d += e;
    }
    if (lane == 0) den[wid] = d;
}

__global__ __launch_bounds__(256) void attn_agg_kernel(
    const unsigned short* __restrict__ Vb,
    const float* __restrict__ scores, const float* __restrict__ den,
    const int* __restrict__ row_off, const int* __restrict__ csr_src,
    float* __restrict__ agg, int n_nodes, int n_edges)
{
    const int wid = (int)((blockIdx.x * 256 + threadIdx.x) >> 6);
    const int lane = threadIdx.x & 63;
    if (wid >= n_nodes) return;

    int beg = row_off[wid], end = row_off[wid + 1];
    beg = max(0, min(beg, n_edges));
    end = max(beg, min(end, n_edges));
    float a0 = 0.f, a1 = 0.f;

    for (int i = beg; i < end; ++i) {
        int s = csr_src[i];
        s = max(0, min(s, n_nodes - 1));
        float e = scores[i];
        unsigned vv = *(const unsigned*)(Vb + (size_t)s * HDIM + 2 * lane);
        a0 = fmaf(e, b2f_lo(vv), a0);
        a1 = fmaf(e, b2f_hi(vv), a1);
    }
    float inv = 1.f / (den[wid] + 1e-8f);
    *(float2*)(agg + (size_t)wid * HDIM + 2 * lane) = make_float2(a0 * inv, a1 * inv);
}

// =====================================================================
// K6: out = agg@Wo + bo; x = emb + out; LayerNorm -> FP32 d_out in-place.
// =====================================================================
__global__ __launch_bounds__(256) void out_ln_kernel(
    const float* __restrict__ emb,
    const float* __restrict__ cw,
    float* __restrict__ out, int n_nodes)
{
    __shared__ float lds[HDIM * 32];
    const int tid = threadIdx.x;
    const int nbase = blockIdx.x * 32;

    for (int idx = tid; idx < 32 * HDIM; idx += 256) {
        int m = idx >> 7;
        int t = idx & 127;
        int node = nbase + m;
        lds[t * 32 + m] = (node < n_nodes) ? out[(size_t)node * HDIM + t] : 0.f;
    }
    __syncthreads();

    const int c = tid & 31;
    const int g = tid >> 5;
    const float* Wo = cw + CW_WO;

    float acc[4][4] = {{0.f}};
    for (int t = 0; t < HDIM; ++t) {
        float4 r = *(const float4*)(lds + t * 32 + 4 * g);
        float rr[4] = { r.x, r.y, r.z, r.w };
        float4 w4 = *(const float4*)(Wo + t * HDIM + 4 * c);
        float wa[4] = { w4.x, w4.y, w4.z, w4.w };
        #pragma unroll
        for (int m = 0; m < 4; ++m)
            #pragma unroll
            for (int j = 0; j < 4; ++j)
                acc[m][j] = fmaf(rr[m], wa[j], acc[m][j]);
    }

    float4 bo4 = *(const float4*)(cw + CW_BO + 4 * c);
    float4 ga4 = *(const float4*)(cw + CW_GA + 4 * c);
    float4 be4 = *(const float4*)(cw + CW_BE + 4 * c);
    float boa[4] = { bo4.x, bo4.y, bo4.z, bo4.w };
    float ga[4]  = { ga4.x, ga4.y, ga4.z, ga4.w };
    float ba[4]  = { be4.x, be4.y, be4.z, be4.w };

    #pragma unroll
    for (int m = 0; m < 4; ++m) {
        int node = nbase + 4 * g + m;
        float ea[4] = { 0.f, 0.f, 0.f, 0.f };
        if (node < n_nodes) {
            float4 e4 = *(const float4*)(emb + (size_t)node * HDIM + 4 * c);
            ea[0] = e4.x; ea[1] = e4.y; ea[2] = e4.z; ea[3] = e4.w;
        }

        float x[4], s1 = 0.f, s2 = 0.f;
        #pragma unroll
        for (int j = 0; j < 4; ++j) {
            x[j] = ea[j] + acc[m][j] + boa[j];
            s1 += x[j];
            s2 = fmaf(x[j], x[j], s2);
        }
        #pragma unroll
        for (int mask = 1; mask <= 16; mask <<= 1) {
            s1 += __shfl_xor(s1, mask);
            s2 += __shfl_xor(s2, mask);
        }
        float mu = s1 * (1.f / 128.f);
        float var = fmaxf(s2 * (1.f / 128.f) - mu * mu, 0.f);
        float rs = rsqrtf(var + 1e-5f);
        if (node < n_nodes) {
            float4 o;
            o.x = ga[0] * (x[0] - mu) * rs + ba[0];
            o.y = ga[1] * (x[1] - mu) * rs + ba[1];
            o.z = ga[2] * (x[2] - mu) * rs + ba[2];
            o.w = ga[3] * (x[3] - mu) * rs + ba[3];
            *(float4*)(out + (size_t)node * HDIM + 4 * c) = o;
        }
    }
}

// =====================================================================
extern "C" void kernel_launch(void* const* d_in, const int* in_sizes, int n_in,
                              void* d_out, int out_size, void* d_ws, size_t ws_size,
                              hipStream_t stream)
{
    const float* physics = (const float*)d_in[0];
    const float* emb     = (const float*)d_in[1];
    const int*   ei      = (const int*)d_in[2];

    const int n_nodes = in_sizes[1] / HDIM;
    const int n_edges = in_sizes[2] / 2;
    const int NB = (n_nodes + 255) / 256;

    char* ws = (char*)d_ws;
    size_t off = 0;
    auto alloc = [&](size_t bytes) -> void* {
        void* p = ws + off;
        off = (off + bytes + 255) & ~(size_t)255;
        return p;
    };

    // common buffers
    float* cw      = (float*)alloc((size_t)CW_TOTAL * 4);
    unsigned short* wfrag = (unsigned short*)alloc((size_t)3 * 5 * 8 * 64 * 8 * 2); // 123 KB
    int* deg       = (int*)alloc((size_t)2 * n_nodes * 4);   // deg + cursor
    int* cursor    = deg + n_nodes;
    int* row_off   = (int*)alloc((size_t)(n_nodes + 1) * 4);
    int* bsum      = (int*)alloc((size_t)NB * 4);
    int* boff      = (int*)alloc((size_t)NB * 4);
    int* csr_src   = (int*)alloc((size_t)n_edges * 4);
    unsigned short* Kb = (unsigned short*)alloc((size_t)n_nodes * HDIM * 2);
    unsigned short* Vb = (unsigned short*)alloc((size_t)n_nodes * HDIM * 2);
    size_t common_off = off;

    // fused path extra: Q buffer (25.6 MB)
    unsigned short* Qb = (unsigned short*)alloc((size_t)n_nodes * HDIM * 2);
    size_t fused_need = off;

    bool fused = (ws_size >= fused_need);
    float* scores = nullptr; float* den = nullptr;
    if (!fused) {
        off = common_off;
        scores = (float*)alloc((size_t)n_edges * 4);
        den    = (float*)alloc((size_t)n_nodes * 4);
        if (ws_size < off) {
            int bucket = (int)min((size_t)255, ws_size >> 24);
            ws_sentinel_kernel<<<1, 64, 0, stream>>>((float*)d_out, bucket);
            return;
        }
    }

    hipMemsetAsync(deg, 0, (size_t)2 * n_nodes * sizeof(int), stream);

    convert_weights<<<(CW_TOTAL + 255) / 256, 256, 0, stream>>>(
        (const float*)d_in[3], (const float*)d_in[5], (const float*)d_in[7],
        (const float*)d_in[9], (const float*)d_in[4], (const float*)d_in[6],
        (const float*)d_in[8], (const float*)d_in[10], (const float*)d_in[11],
        (const float*)d_in[12], cw);

    if (fused) {
        pack_wfrag<<<(3 * 5 * 8 * 64 + 255) / 256, 256, 0, stream>>>(cw, wfrag);
        qkv_mfma_kernel<<<(n_nodes + 63) / 64, 256, 0, stream>>>(
            physics, emb, cw, wfrag, Qb, Kb, Vb, n_nodes);
    } else {
        qkv_kernel<<<(n_nodes + 31) / 32, 256, 0, stream>>>(
            physics, emb, cw, Kb /*unused*/, Kb, Vb, n_nodes, 0);
    }

    degree_kernel<<<(n_edges + 255) / 256, 256, 0, stream>>>(ei, deg, n_edges, n_nodes);
    scan_bsum<<<NB, 256, 0, stream>>>(deg, bsum, n_nodes);
    scan_boff<<<1, 512, 0, stream>>>(bsum, boff, NB);
    scan_final<<<NB, 256, 0, stream>>>(deg, boff, row_off, n_nodes);
    fill_kernel<<<(n_edges + 255) / 256, 256, 0, stream>>>(ei, row_off, cursor, csr_src, n_edges, n_nodes);

    if (fused) {
        attn_fused_kernel<<<(n_nodes + 3) / 4, 256, 0, stream>>>(
            Qb, Kb, Vb, row_off, csr_src, (float*)d_out, n_nodes, n_edges);
    } else {
        attn_score_kernel<<<(n_nodes + 3) / 4, 256, 0, stream>>>(
            physics, emb, cw, Kb, row_off, csr_src, scores, den, n_nodes, n_edges);
        attn_agg_kernel<<<(n_nodes + 3) / 4, 256, 0, stream>>>(
            Vb, scores, den, row_off, csr_src, (float*)d_out, n_nodes, n_edges);
    }

    out_ln_kernel<<<(n_nodes + 31) / 32, 256, 0, stream>>>(
        emb, cw, (float*)d_out, n_nodes);
}

// Round 9
// 605.742 us; speedup vs baseline: 1.8008x; 1.0691x over previous
//
#include <hip/hip_runtime.h>
#include <hip/hip_bf16.h>
#include <math.h>

#define PDIM 10
#define HDIM 128
#define TDIM 138   // PDIM + HDIM
#define AROW 168   // A-tile LDS row stride in bf16 (160 K-pad + 8)
#define A_SH (64 * AROW)            // 10752 shorts = 21504 B
#define B_SH (A_SH)                 // B region offset (shorts)
#define B_LEN (5 * 8 * 64 * 8)      // 20480 shorts = 40960 B (one mat)
#define T_SH (A_SH + B_LEN)         // transpose region offset (shorts)
#define TROW 136                    // transpose row stride (shorts), 272 B = 17*16
#define SMEM_SH (T_SH + 64 * TROW)  // 39936 shorts = 79872 B

// converted-weights layout (fp32, in ws)
#define CW_WQ 0
#define CW_WK 17664
#define CW_WV 35328
#define CW_WO 51712
#define CW_BQ 68096
#define CW_BK 68224
#define CW_BV 68352
#define CW_BO 68480
#define CW_GA 68608
#define CW_BE 68736
#define CW_TOTAL 68864

typedef short v8s __attribute__((ext_vector_type(8)));   // 8 bf16
typedef float v4f __attribute__((ext_vector_type(4)));   // MFMA acc

// ---------- bf16 helpers ----------
__device__ __forceinline__ float b2f_lo(unsigned u) { return __uint_as_float(u << 16); }
__device__ __forceinline__ float b2f_hi(unsigned u) { return __uint_as_float(u & 0xffff0000u); }
__device__ __forceinline__ unsigned short f2b(float f) {
    unsigned u = __float_as_uint(f);
    u += 0x7fffu + ((u >> 16) & 1u);
    return (unsigned short)(u >> 16);
}
__device__ __forceinline__ void store4bf(unsigned short* p, float a, float b, float c, float d) {
    ushort4 v; v.x = f2b(a); v.y = f2b(b); v.z = f2b(c); v.w = f2b(d);
    *(ushort4*)p = v;
}

__global__ void ws_sentinel_kernel(float* out, int bucket)
{
    if (threadIdx.x == 0) out[0] = ldexpf(1.f + (float)bucket / 256.f, 100);
}

// =====================================================================
// K0: gather weights/biases/gamma/beta (fp32) into one contiguous block.
// =====================================================================
__global__ __launch_bounds__(256) void convert_weights(
    const float* Wq, const float* Wk, const float* Wv, const float* Wo,
    const float* bq, const float* bk, const float* bv, const float* bo,
    const float* ga, const float* be,
    float* __restrict__ dst)
{
    int idx = blockIdx.x * 256 + threadIdx.x;
    if (idx >= CW_TOTAL) return;
    const float* src; int loc;
    if      (idx < CW_WK) { src = Wq; loc = idx - CW_WQ; }
    else if (idx < CW_WV) { src = Wk; loc = idx - CW_WK; }
    else if (idx < CW_WO) { src = Wv; loc = idx - CW_WV; }
    else if (idx < CW_BQ) { src = Wo; loc = idx - CW_WO; }
    else if (idx < CW_BK) { src = bq; loc = idx - CW_BQ; }
    else if (idx < CW_BV) { src = bk; loc = idx - CW_BK; }
    else if (idx < CW_BO) { src = bv; loc = idx - CW_BV; }
    else if (idx < CW_GA) { src = bo; loc = idx - CW_BO; }
    else if (idx < CW_BE) { src = ga; loc = idx - CW_GA; }
    else                  { src = be; loc = idx - CW_BE; }
    dst[idx] = src[loc];
}

// =====================================================================
// K0c: pack Wq/Wk/Wv' into MFMA B-fragment-major bf16:
// wfrag[mat][kc][nt][lane][j]; B-element (k=kc*32+(lane>>4)*8+j,
// n=nt*16+(lane&15)).  For V rows k<PDIM are zero (concat shift).
// =====================================================================
__global__ __launch_bounds__(256) void pack_wfrag(
    const float* __restrict__ cw, unsigned short* __restrict__ wfrag)
{
    int g = blockIdx.x * 256 + threadIdx.x;
    if (g >= 3 * 5 * 8 * 64) return;
    int lane = g & 63;
    int nt   = (g >> 6) & 7;
    int mk   = g >> 9;            // mat*5 + kc
    int kc = mk % 5, mat = mk / 5;
    int quad = lane >> 4, l15 = lane & 15;
    int n = nt * 16 + l15;

    unsigned short* dst = wfrag + (size_t)g * 8;
    #pragma unroll
    for (int j = 0; j < 8; ++j) {
        int k = kc * 32 + quad * 8 + j;
        float v = 0.f;
        if (mat == 0)      { if (k < TDIM) v = cw[CW_WQ + k * HDIM + n]; }
        else if (mat == 1) { if (k < TDIM) v = cw[CW_WK + k * HDIM + n]; }
        else               { if (k >= PDIM && k < TDIM) v = cw[CW_WV + (k - PDIM) * HDIM + n]; }
        dst[j] = f2b(v);
    }
}

// =====================================================================
// K1-MFMA v2: fused Q,K,V GEMMs, LDS-staged B, per-mat accumulation.
// Block = 4 waves, tile = 64 nodes x 128 cols, K=160 (5 chunks of 32).
// Per mat: 40 KB B slice lives in LDS (bulk-prefetched to regs during
// the previous mat's MFMA loop); inner loop is ds_read-only.
//   A frag: row=w*16+(lane&15), k=quad*8+j   (LDS, hoisted to 5 regs)
//   B frag: col=nt*16+(lane&15), k=quad*8+j  (LDS)
//   D:      col=lane&15, row=quad*4+reg      [verified R8]
// Epilogue: bias added in D-layout, bf16 transpose via LDS, 16B copy out.
// =====================================================================
__global__ __launch_bounds__(256) void qkv_mfma_kernel(
    const float* __restrict__ physics, const float* __restrict__ emb,
    const float* __restrict__ cw, const unsigned short* __restrict__ wfrag,
    unsigned short* __restrict__ Qb, unsigned short* __restrict__ Kb,
    unsigned short* __restrict__ Vb, int n_nodes)
{
    __shared__ __align__(16) unsigned short smem[SMEM_SH];

    const int tid = threadIdx.x;
    const int nbase = blockIdx.x * 64;
    const int lane = tid & 63;
    const int w = tid >> 6;
    const int quad = lane >> 4;
    const int l15 = lane & 15;

    // ---- prefetch B(mat=0) into regs ----
    uint4 breg[10];
    {
        const uint4* gsrc = (const uint4*)wfrag;   // mat 0
        #pragma unroll
        for (int i = 0; i < 10; ++i) breg[i] = gsrc[i * 256 + tid];
    }

    // ---- stage A (fp32 -> bf16 pairs), zero-pad k>=138 / rows >= n ----
    for (int idx = tid; idx < 64 * 84; idx += 256) {
        int r = idx / 84, p = idx - r * 84;     // pair p covers k=2p,2p+1
        int node = nbase + r;
        float v0 = 0.f, v1 = 0.f;
        if (node < n_nodes) {
            int k = 2 * p;
            if (k + 1 < PDIM) {
                const float* ph = physics + node * PDIM + k;
                v0 = ph[0]; v1 = ph[1];
            } else if (k < TDIM) {
                const float* em = emb + (size_t)node * HDIM + (k - PDIM);
                v0 = em[0]; v1 = em[1];
            }
        }
        ((unsigned*)smem)[r * 84 + p] = (unsigned)f2b(v0) | ((unsigned)f2b(v1) << 16);
    }

    // ---- write B(0) into LDS ----
    {
        uint4* bdst = (uint4*)(smem + B_SH);
        #pragma unroll
        for (int i = 0; i < 10; ++i) bdst[i * 256 + tid] = breg[i];
    }
    __syncthreads();

    // ---- hoist A fragments (same for all 3 mats) ----
    v8s a_frag[5];
    #pragma unroll
    for (int kc = 0; kc < 5; ++kc)
        a_frag[kc] = *(v8s*)(smem + (w * 16 + l15) * AROW + kc * 32 + quad * 8);

    const int r_out = tid >> 2;
    const int cseg = (tid & 3) * 32;
    const int node_out = nbase + r_out;

    for (int mat = 0; mat < 3; ++mat) {
        // prefetch next mat's B slice into regs (global loads, no LDS touch)
        if (mat < 2) {
            const uint4* gsrc = (const uint4*)(wfrag + (size_t)(mat + 1) * B_LEN);
            #pragma unroll
            for (int i = 0; i < 10; ++i) breg[i] = gsrc[i * 256 + tid];
        }

        // ---- MFMA: 8 col-tiles x 5 k-chunks, all operands in LDS/regs ----
        v4f acc[8];
        #pragma unroll
        for (int nt = 0; nt < 8; ++nt) acc[nt] = (v4f){0.f, 0.f, 0.f, 0.f};

        #pragma unroll
        for (int kc = 0; kc < 5; ++kc) {
            #pragma unroll
            for (int nt = 0; nt < 8; ++nt) {
                v8s b = *(v8s*)(smem + B_SH + ((kc * 8 + nt) * 64 + lane) * 8);
                acc[nt] = __builtin_amdgcn_mfma_f32_16x16x32_bf16(
                    a_frag[kc], b, acc[nt], 0, 0, 0);
            }
        }

        // ---- bias in D-layout, bf16 transpose into T region ----
        #pragma unroll
        for (int nt = 0; nt < 8; ++nt) {
            float bias = cw[CW_BQ + mat * HDIM + nt * 16 + l15];
            #pragma unroll
            for (int reg = 0; reg < 4; ++reg) {
                int row = w * 16 + quad * 4 + reg;
                smem[T_SH + row * TROW + nt * 16 + l15] = f2b(acc[nt][reg] + bias);
            }
        }
        __syncthreads();   // T complete; B(mat) reads done

        // ---- copy T rows to global (16B aligned) + stage B(mat+1) ----
        if (node_out < n_nodes) {
            unsigned short* dst = (mat == 0 ? Qb : (mat == 1 ? Kb : Vb))
                                  + (size_t)node_out * HDIM + cseg;
            const unsigned short* srcp = smem + T_SH + r_out * TROW + cseg;
            #pragma unroll
            for (int j = 0; j < 4; ++j)
                ((uint4*)dst)[j] = *(const uint4*)(srcp + 8 * j);
        }
        if (mat < 2) {
            uint4* bdst = (uint4*)(smem + B_SH);
            #pragma unroll
            for (int i = 0; i < 10; ++i) bdst[i * 256 + tid] = breg[i];
        }
        __syncthreads();   // B(mat+1) ready; T readers done
    }
}

// =====================================================================
// K1 fallback (VALU QKV, proven path; used only if ws too small)
// =====================================================================
__global__ __launch_bounds__(256) void qkv_kernel(
    const float* __restrict__ physics, const float* __restrict__ emb,
    const float* __restrict__ cw,
    unsigned short* __restrict__ Kb, unsigned short* __restrict__ Vb,
    int n_nodes)
{
    __shared__ float lds[TDIM * 32];
    const int tid = threadIdx.x;
    const int nbase = blockIdx.x * 32;

    for (int idx = tid; idx < 32 * TDIM; idx += 256) {
        int m = idx / TDIM;
        int t = idx - m * TDIM;
        int node = nbase + m;
        float v = 0.f;
        if (node < n_nodes)
            v = (t < PDIM) ? physics[node * PDIM + t]
                           : emb[(size_t)node * HDIM + (t - PDIM)];
        lds[t * 32 + m] = v;
    }
    __syncthreads();

    const int c = tid & 31;
    const int g = tid >> 5;
    const float* Wk = cw + CW_WK;
    const float* Wv = cw + CW_WV;

    float ak[4][4] = {{0.f}}, av[4][4] = {{0.f}};

    for (int t = 0; t < TDIM; ++t) {
        float4 r = *(const float4*)(lds + t * 32 + 4 * g);
        float rr[4] = { r.x, r.y, r.z, r.w };
        float4 wk4 = *(const float4*)(Wk + t * HDIM + 4 * c);
        float wka[4] = { wk4.x, wk4.y, wk4.z, wk4.w };
        #pragma unroll
        for (int m = 0; m < 4; ++m)
            #pragma unroll
            for (int j = 0; j < 4; ++j)
                ak[m][j] = fmaf(rr[m], wka[j], ak[m][j]);
        if (t >= PDIM) {
            float4 wv4 = *(const float4*)(Wv + (t - PDIM) * HDIM + 4 * c);
            float wva[4] = { wv4.x, wv4.y, wv4.z, wv4.w };
            #pragma unroll
            for (int m = 0; m < 4; ++m)
                #pragma unroll
                for (int j = 0; j < 4; ++j)
                    av[m][j] = fmaf(rr[m], wva[j], av[m][j]);
        }
    }

    float4 bk4 = *(const float4*)(cw + CW_BK + 4 * c);
    float4 bv4 = *(const float4*)(cw + CW_BV + 4 * c);

    #pragma unroll
    for (int m = 0; m < 4; ++m) {
        int node = nbase + 4 * g + m;
        if (node >= n_nodes) continue;
        size_t o = (size_t)node * HDIM + 4 * c;
        store4bf(Kb + o, ak[m][0] + bk4.x, ak[m][1] + bk4.y, ak[m][2] + bk4.z, ak[m][3] + bk4.w);
        store4bf(Vb + o, av[m][0] + bv4.x, av[m][1] + bv4.y, av[m][2] + bv4.z, av[m][3] + bv4.w);
    }
}

// =====================================================================
// CSR build
// =====================================================================
__global__ __launch_bounds__(256) void degree_kernel(
    const int* __restrict__ ei, int* __restrict__ deg, int n_edges, int n_nodes)
{
    int e = blockIdx.x * 256 + threadIdx.x;
    if (e < n_edges) {
        int d = ei[n_edges + e];
        d = max(0, min(d, n_nodes - 1));
        atomicAdd(&deg[d], 1);
    }
}

__global__ __launch_bounds__(256) void scan_bsum(
    const int* __restrict__ deg, int* __restrict__ bsum, int n)
{
    __shared__ int s[256];
    int i = blockIdx.x * 256 + threadIdx.x;
    s[threadIdx.x] = (i < n) ? deg[i] : 0;
    __syncthreads();
    for (int off = 128; off > 0; off >>= 1) {
        if (threadIdx.x < off) s[threadIdx.x] += s[threadIdx.x + off];
        __syncthreads();
    }
    if (threadIdx.x == 0) bsum[blockIdx.x] = s[0];
}

__global__ __launch_bounds__(512) void scan_boff(
    const int* __restrict__ bsum, int* __restrict__ boff, int nb)
{
    __shared__ int s[512];
    int t = threadIdx.x;
    int v = (t < nb) ? bsum[t] : 0;
    s[t] = v;
    __syncthreads();
    for (int off = 1; off < 512; off <<= 1) {
        int u = (t >= off) ? s[t - off] : 0;
        __syncthreads();
        s[t] += u;
        __syncthreads();
    }
    if (t < nb) boff[t] = s[t] - v;
}

__global__ __launch_bounds__(256) void scan_final(
    const int* __restrict__ deg, const int* __restrict__ boff,
    int* __restrict__ row_off, int n)
{
    __shared__ int s[256];
    int t = threadIdx.x;
    int i = blockIdx.x * 256 + t;
    int v = (i < n) ? deg[i] : 0;
    s[t] = v;
    __syncthreads();
    for (int off = 1; off < 256; off <<= 1) {
        int u = (t >= off) ? s[t - off] : 0;
        __syncthreads();
        s[t] += u;
        __syncthreads();
    }
    int base = boff[blockIdx.x];
    if (i < n) row_off[i] = base + s[t] - v;
    if (i == n - 1) row_off[n] = base + s[t];
}

__global__ __launch_bounds__(256) void fill_kernel(
    const int* __restrict__ ei, const int* __restrict__ row_off,
    int* __restrict__ cursor, int* __restrict__ csr_src, int n_edges, int n_nodes)
{
    int e = blockIdx.x * 256 + threadIdx.x;
    if (e < n_edges) {
        int d = ei[n_edges + e];
        d = max(0, min(d, n_nodes - 1));
        int pos = atomicAdd(&cursor[d], 1);
        csr_src[row_off[d] + pos] = ei[e];
    }
}

// =====================================================================
// K5: FUSED attention (R7, unchanged).
// =====================================================================
__global__ __launch_bounds__(256) void attn_fused_kernel(
    const unsigned short* __restrict__ Qb, const unsigned short* __restrict__ Kb,
    const unsigned short* __restrict__ Vb,
    const int* __restrict__ row_off, const int* __restrict__ csr_src,
    float* __restrict__ agg, int n_nodes, int n_edges)
{
    const int wid = (int)((blockIdx.x * 256 + threadIdx.x) >> 6);
    const int lane = threadIdx.x & 63;
    if (wid >= n_nodes) return;
    const int eg = lane >> 4;
    const int cg = lane & 15;

    const float scale = 0.088388347648318447f;   // 1/sqrt(128)
    uint4 qr = *(const uint4*)(Qb + (size_t)wid * HDIM + 8 * cg);
    float q[8];
    q[0] = b2f_lo(qr.x) * scale; q[1] = b2f_hi(qr.x) * scale;
    q[2] = b2f_lo(qr.y) * scale; q[3] = b2f_hi(qr.y) * scale;
    q[4] = b2f_lo(qr.z) * scale; q[5] = b2f_hi(qr.z) * scale;
    q[6] = b2f_lo(qr.w) * scale; q[7] = b2f_hi(qr.w) * scale;

    int beg = row_off[wid], end = row_off[wid + 1];
    beg = max(0, min(beg, n_edges));
    end = max(beg, min(end, n_edges));

    float acc[8] = {0.f,0.f,0.f,0.f,0.f,0.f,0.f,0.f};
    float den = 0.f;

    for (int i = beg; i < end; i += 4) {
        int idx = i + eg;
        bool valid = idx < end;
        int s = csr_src[valid ? idx : (end - 1)];
        s = max(0, min(s, n_nodes - 1));
        uint4 kr = *(const uint4*)(Kb + (size_t)s * HDIM + 8 * cg);
        uint4 vr = *(const uint4*)(Vb + (size_t)s * HDIM + 8 * cg);

        float p;
        p = q[0] * b2f_lo(kr.x);
        p = fmaf(q[1], b2f_hi(kr.x), p);
        p = fmaf(q[2], b2f_lo(kr.y), p);
        p = fmaf(q[3], b2f_hi(kr.y), p);
        p = fmaf(q[4], b2f_lo(kr.z), p);
        p = fmaf(q[5], b2f_hi(kr.z), p);
        p = fmaf(q[6], b2f_lo(kr.w), p);
        p = fmaf(q[7], b2f_hi(kr.w), p);
        p += __shfl_xor(p, 1);
        p += __shfl_xor(p, 2);
        p += __shfl_xor(p, 4);
        p += __shfl_xor(p, 8);

        float e = valid ? __expf(fminf(p, 60.f)) : 0.f;
        den += e;
        acc[0] = fmaf(e, b2f_lo(vr.x), acc[0]);
        acc[1] = fmaf(e, b2f_hi(vr.x), acc[1]);
        acc[2] = fmaf(e, b2f_lo(vr.y), acc[2]);
        acc[3] = fmaf(e, b2f_hi(vr.y), acc[3]);
        acc[4] = fmaf(e, b2f_lo(vr.z), acc[4]);
        acc[5] = fmaf(e, b2f_hi(vr.z), acc[5]);
        acc[6] = fmaf(e, b2f_lo(vr.w), acc[6]);
        acc[7] = fmaf(e, b2f_hi(vr.w), acc[7]);
    }

    #pragma unroll
    for (int j = 0; j < 8; ++j) {
        acc[j] += __shfl_xor(acc[j], 16);
        acc[j] += __shfl_xor(acc[j], 32);
    }
    den += __shfl_xor(den, 16);
    den += __shfl_xor(den, 32);

    float inv = 1.f / (den + 1e-8f);
    if (eg == 0) {
        float* dst = agg + (size_t)wid * HDIM + 8 * cg;
        *(float4*)dst       = make_float4(acc[0]*inv, acc[1]*inv, acc[2]*inv, acc[3]*inv);
        *(float4*)(dst + 4) = make_float4(acc[4]*inv, acc[5]*inv, acc[6]*inv, acc[7]*inv);
    }
}

// =====================================================================
// Fallback split attention (R6 path)
// =====================================================================
__global__ __launch_bounds__(256) void attn_score_kernel(
    const float* __restrict__ physics, const float* __restrict__ emb,
    const float* __restrict__ cw,
    const unsigned short* __restrict__ Kb,
    const int* __restrict__ row_off, const int* __restrict__ csr_src,
    float* __restrict__ scores, float* __restrict__ den,
    int n_nodes, int n_edges)
{
    __shared__ float fullr[4][TDIM];
    __shared__ float qs[4][HDIM];
    const int tid = threadIdx.x;
    const int nb = blockIdx.x * 4;

    for (int idx = tid; idx < 4 * TDIM; idx += 256) {
        int n = idx / TDIM, t = idx - n * TDIM;
        int node = nb + n;
        float v = 0.f;
        if (node < n_nodes)
            v = (t < PDIM) ? physics[node * PDIM + t]
                           : emb[(size_t)node * HDIM + t - PDIM];
        fullr[n][t] = v;
    }
    __syncthreads();

    const float scale = 0.088388347648318447f;
    for (int o = tid; o < 4 * HDIM; o += 256) {
        int n = o >> 7, c = o & 127;
        float acc = cw[CW_BQ + c];
        const float* w = cw + CW_WQ + c;
        for (int t = 0; t < TDIM; ++t)
            acc = fmaf(fullr[n][t], w[t * HDIM], acc);
        qs[n][c] = acc * scale;
    }
    __syncthreads();

    const int wv = tid >> 6;
    const int lane = tid & 63;
    const int wid = nb + wv;
    if (wid >= n_nodes) return;

    float q0 = qs[wv][2 * lane], q1 = qs[wv][2 * lane + 1];
    int beg = row_off[wid], end = row_off[wid + 1];
    beg = max(0, min(beg, n_edges));
    end = max(beg, min(end, n_edges));
    float d = 0.f;

    for (int i = beg; i < end; ++i) {
        int s = csr_src[i];
        s = max(0, min(s, n_nodes - 1));
        unsigned kk = *(const unsigned*)(Kb + (size_t)s * HDIM + 2 * lane);
        float p = fmaf(q0, b2f_lo(kk), q1 * b2f_hi(kk));
        p += __shfl_xor(p, 1);
        p += __shfl_xor(p, 2);
        p += __shfl_xor(p, 4);
        p += __shfl_xor(p, 8);
        p += __shfl_xor(p, 16);
        p += __shfl_xor(p, 32);
        float e = __expf(fminf(p, 30.f));
        if (lane == 0) scores[i] = e;
        d += e;
    }
    if (lane == 0) den[wid] = d;
}

__global__ __launch_bounds__(256) void attn_agg_kernel(
    const unsigned short* __restrict__ Vb,
    const float* __restrict__ scores, const float* __restrict__ den,
    const int* __restrict__ row_off, const int* __restrict__ csr_src,
    float* __restrict__ agg, int n_nodes, int n_edges)
{
    const int wid = (int)((blockIdx.x * 256 + threadIdx.x) >> 6);
    const int lane = threadIdx.x & 63;
    if (wid >= n_nodes) return;

    int beg = row_off[wid], end = row_off[wid + 1];
    beg = max(0, min(beg, n_edges));
    end = max(beg, min(end, n_edges));
    float a0 = 0.f, a1 = 0.f;

    for (int i = beg; i < end; ++i) {
        int s = csr_src[i];
        s = max(0, min(s, n_nodes - 1));
        float e = scores[i];
        unsigned vv = *(const unsigned*)(Vb + (size_t)s * HDIM + 2 * lane);
        a0 = fmaf(e, b2f_lo(vv), a0);
        a1 = fmaf(e, b2f_hi(vv), a1);
    }
    float inv = 1.f / (den[wid] + 1e-8f);
    *(float2*)(agg + (size_t)wid * HDIM + 2 * lane) = make_float2(a0 * inv, a1 * inv);
}

// =====================================================================
// K6: out = agg@Wo + bo; x = emb + out; LayerNorm -> FP32 d_out in-place.
// =====================================================================
__global__ __launch_bounds__(256) void out_ln_kernel(
    const float* __restrict__ emb,
    const float* __restrict__ cw,
    float* __restrict__ out, int n_nodes)
{
    __shared__ float lds[HDIM * 32];
    const int tid = threadIdx.x;
    const int nbase = blockIdx.x * 32;

    for (int idx = tid; idx < 32 * HDIM; idx += 256) {
        int m = idx >> 7;
        int t = idx & 127;
        int node = nbase + m;
        lds[t * 32 + m] = (node < n_nodes) ? out[(size_t)node * HDIM + t] : 0.f;
    }
    __syncthreads();

    const int c = tid & 31;
    const int g = tid >> 5;
    const float* Wo = cw + CW_WO;

    float acc[4][4] = {{0.f}};
    for (int t = 0; t < HDIM; ++t) {
        float4 r = *(const float4*)(lds + t * 32 + 4 * g);
        float rr[4] = { r.x, r.y, r.z, r.w };
        float4 w4 = *(const float4*)(Wo + t * HDIM + 4 * c);
        float wa[4] = { w4.x, w4.y, w4.z, w4.w };
        #pragma unroll
        for (int m = 0; m < 4; ++m)
            #pragma unroll
            for (int j = 0; j < 4; ++j)
                acc[m][j] = fmaf(rr[m], wa[j], acc[m][j]);
    }

    float4 bo4 = *(const float4*)(cw + CW_BO + 4 * c);
    float4 ga4 = *(const float4*)(cw + CW_GA + 4 * c);
    float4 be4 = *(const float4*)(cw + CW_BE + 4 * c);
    float boa[4] = { bo4.x, bo4.y, bo4.z, bo4.w };
    float ga[4]  = { ga4.x, ga4.y, ga4.z, ga4.w };
    float ba[4]  = { be4.x, be4.y, be4.z, be4.w };

    #pragma unroll
    for (int m = 0; m < 4; ++m) {
        int node = nbase + 4 * g + m;
        float ea[4] = { 0.f, 0.f, 0.f, 0.f };
        if (node < n_nodes) {
            float4 e4 = *(const float4*)(emb + (size_t)node * HDIM + 4 * c);
            ea[0] = e4.x; ea[1] = e4.y; ea[2] = e4.z; ea[3] = e4.w;
        }

        float x[4], s1 = 0.f, s2 = 0.f;
        #pragma unroll
        for (int j = 0; j < 4; ++j) {
            x[j] = ea[j] + acc[m][j] + boa[j];
            s1 += x[j];
            s2 = fmaf(x[j], x[j], s2);
        }
        #pragma unroll
        for (int mask = 1; mask <= 16; mask <<= 1) {
            s1 += __shfl_xor(s1, mask);
            s2 += __shfl_xor(s2, mask);
        }
        float mu = s1 * (1.f / 128.f);
        float var = fmaxf(s2 * (1.f / 128.f) - mu * mu, 0.f);
        float rs = rsqrtf(var + 1e-5f);
        if (node < n_nodes) {
            float4 o;
            o.x = ga[0] * (x[0] - mu) * rs + ba[0];
            o.y = ga[1] * (x[1] - mu) * rs + ba[1];
            o.z = ga[2] * (x[2] - mu) * rs + ba[2];
            o.w = ga[3] * (x[3] - mu) * rs + ba[3];
            *(float4*)(out + (size_t)node * HDIM + 4 * c) = o;
        }
    }
}

// =====================================================================
extern "C" void kernel_launch(void* const* d_in, const int* in_sizes, int n_in,
                              void* d_out, int out_size, void* d_ws, size_t ws_size,
                              hipStream_t stream)
{
    const float* physics = (const float*)d_in[0];
    const float* emb     = (const float*)d_in[1];
    const int*   ei      = (const int*)d_in[2];

    const int n_nodes = in_sizes[1] / HDIM;
    const int n_edges = in_sizes[2] / 2;
    const int NB = (n_nodes + 255) / 256;

    char* ws = (char*)d_ws;
    size_t off = 0;
    auto alloc = [&](size_t bytes) -> void* {
        void* p = ws + off;
        off = (off + bytes + 255) & ~(size_t)255;
        return p;
    };

    // common buffers
    float* cw      = (float*)alloc((size_t)CW_TOTAL * 4);
    unsigned short* wfrag = (unsigned short*)alloc((size_t)3 * B_LEN * 2); // 123 KB
    int* deg       = (int*)alloc((size_t)2 * n_nodes * 4);   // deg + cursor
    int* cursor    = deg + n_nodes;
    int* row_off   = (int*)alloc((size_t)(n_nodes + 1) * 4);
    int* bsum      = (int*)alloc((size_t)NB * 4);
    int* boff      = (int*)alloc((size_t)NB * 4);
    int* csr_src   = (int*)alloc((size_t)n_edges * 4);
    unsigned short* Kb = (unsigned short*)alloc((size_t)n_nodes * HDIM * 2);
    unsigned short* Vb = (unsigned short*)alloc((size_t)n_nodes * HDIM * 2);
    size_t common_off = off;

    // fused path extra: Q buffer (25.6 MB)
    unsigned short* Qb = (unsigned short*)alloc((size_t)n_nodes * HDIM * 2);
    size_t fused_need = off;

    bool fused = (ws_size >= fused_need);
    float* scores = nullptr; float* den = nullptr;
    if (!fused) {
        off = common_off;
        scores = (float*)alloc((size_t)n_edges * 4);
        den    = (float*)alloc((size_t)n_nodes * 4);
        if (ws_size < off) {
            int bucket = (int)min((size_t)255, ws_size >> 24);
            ws_sentinel_kernel<<<1, 64, 0, stream>>>((float*)d_out, bucket);
            return;
        }
    }

    hipMemsetAsync(deg, 0, (size_t)2 * n_nodes * sizeof(int), stream);

    convert_weights<<<(CW_TOTAL + 255) / 256, 256, 0, stream>>>(
        (const float*)d_in[3], (const float*)d_in[5], (const float*)d_in[7],
        (const float*)d_in[9], (const float*)d_in[4], (const float*)d_in[6],
        (const float*)d_in[8], (const float*)d_in[10], (const float*)d_in[11],
        (const float*)d_in[12], cw);

    if (fused) {
        pack_wfrag<<<(3 * 5 * 8 * 64 + 255) / 256, 256, 0, stream>>>(cw, wfrag);
        qkv_mfma_kernel<<<(n_nodes + 63) / 64, 256, 0, stream>>>(
            physics, emb, cw, wfrag, Qb, Kb, Vb, n_nodes);
    } else {
        qkv_kernel<<<(n_nodes + 31) / 32, 256, 0, stream>>>(
            physics, emb, cw, Kb, Vb, n_nodes);
    }

    degree_kernel<<<(n_edges + 255) / 256, 256, 0, stream>>>(ei, deg, n_edges, n_nodes);
    scan_bsum<<<NB, 256, 0, stream>>>(deg, bsum, n_nodes);
    scan_boff<<<1, 512, 0, stream>>>(bsum, boff, NB);
    scan_final<<<NB, 256, 0, stream>>>(deg, boff, row_off, n_nodes);
    fill_kernel<<<(n_edges + 255) / 256, 256, 0, stream>>>(ei, row_off, cursor, csr_src, n_edges, n_nodes);

    if (fused) {
        attn_fused_kernel<<<(n_nodes + 3) / 4, 256, 0, stream>>>(
            Qb, Kb, Vb, row_off, csr_src, (float*)d_out, n_nodes, n_edges);
    } else {
        attn_score_kernel<<<(n_nodes + 3) / 4, 256, 0, stream>>>(
            physics, emb, cw, Kb, row_off, csr_src, scores, den, n_nodes, n_edges);
        attn_agg_kernel<<<(n_nodes + 3) / 4, 256, 0, stream>>>(
            Vb, scores, den, row_off, csr_src, (float*)d_out, n_nodes, n_edges);
    }

    out_ln_kernel<<<(n_nodes + 31) / 32, 256, 0, stream>>>(
        emb, cw, (float*)d_out, n_nodes);
}

// Round 10
// 560.749 us; speedup vs baseline: 1.9452x; 1.0802x over previous
//
#include <hip/hip_runtime.h>
#include <hip/hip_bf16.h>
#include <math.h>

#define PDIM 10
#define HDIM 128
#define TDIM 138   // PDIM + HDIM
#define AROW 168   // A-tile LDS row stride in bf16
#define A_SH (64 * AROW)
#define B_SH (A_SH)
#define B_LEN (5 * 8 * 64 * 8)
#define T_SH (A_SH + B_LEN)
#define TROW 136
#define SMEM_SH (T_SH + 64 * TROW)

// converted-weights layout (fp32, in ws)
#define CW_WQ 0
#define CW_WK 17664
#define CW_WV 35328
#define CW_WO 51712
#define CW_BQ 68096
#define CW_BK 68224
#define CW_BV 68352
#define CW_BO 68480
#define CW_GA 68608
#define CW_BE 68736
#define CW_TOTAL 68864

typedef short v8s __attribute__((ext_vector_type(8)));
typedef float v4f __attribute__((ext_vector_type(4)));
typedef float v2f __attribute__((ext_vector_type(2)));

#if defined(__has_builtin)
#if __has_builtin(__builtin_amdgcn_cvt_pk_f32_fp8) && __has_builtin(__builtin_amdgcn_cvt_pk_fp8_f32)
#define HAVE_FP8_CVT 1
#endif
#endif
#ifndef HAVE_FP8_CVT
#define HAVE_FP8_CVT 0
#endif

// ---------- bf16 helpers ----------
__device__ __forceinline__ float b2f_lo(unsigned u) { return __uint_as_float(u << 16); }
__device__ __forceinline__ float b2f_hi(unsigned u) { return __uint_as_float(u & 0xffff0000u); }
__device__ __forceinline__ unsigned short f2b(float f) {
    unsigned u = __float_as_uint(f);
    u += 0x7fffu + ((u >> 16) & 1u);
    return (unsigned short)(u >> 16);
}

// ---------- fp8 e4m3fn helpers (manual fallbacks are bit-faithful) ----------
__device__ __forceinline__ float f8_dec1(unsigned b) {
    unsigned e = (b >> 3) & 0xf, m = b & 7;
    float v = e ? __uint_as_float(((e + 120) << 23) | (m << 20))
                : (float)m * 0.001953125f;          // subnormal: m * 2^-9
    return (b & 0x80) ? -v : v;
}
__device__ __forceinline__ unsigned f8_enc1(float f) {
    unsigned u = __float_as_uint(f);
    unsigned s = (u >> 31) << 7;
    float a = fabsf(f);
    if (a < 0.0009765625f) return s;                // < 2^-10 -> 0
    if (a < 0.015625f) {                            // subnormal grid 2^-9
        int m = (int)(a * 512.f + 0.5f); if (m > 7) m = 7;
        return s | (unsigned)m;
    }
    if (a >= 448.f) return s | 0x7e;
    int ex = (int)((u >> 23) & 0xff);
    unsigned mant = u & 0x7fffff;
    unsigned r = mant >> 20, rem = mant & 0xfffff;
    if (rem > 0x80000u || (rem == 0x80000u && (r & 1))) r++;
    if (r == 8) { r = 0; ex++; }
    if (ex - 127 > 8) return s | 0x7e;
    return s | (unsigned)((ex - 120) << 3) | r;
}

// accumulate dot of 4 fp8 (one uint) against q[0..3]
__device__ __forceinline__ void dot4(unsigned w, const float* q, float& p) {
#if HAVE_FP8_CVT
    v2f lo = __builtin_amdgcn_cvt_pk_f32_fp8((int)w, false);
    v2f hi = __builtin_amdgcn_cvt_pk_f32_fp8((int)w, true);
    p = fmaf(q[0], lo[0], p); p = fmaf(q[1], lo[1], p);
    p = fmaf(q[2], hi[0], p); p = fmaf(q[3], hi[1], p);
#else
    p = fmaf(q[0], f8_dec1(w & 0xff), p);
    p = fmaf(q[1], f8_dec1((w >> 8) & 0xff), p);
    p = fmaf(q[2], f8_dec1((w >> 16) & 0xff), p);
    p = fmaf(q[3], f8_dec1(w >> 24), p);
#endif
}
// acc[0..3] += e * decode4(w)
__device__ __forceinline__ void acc4(unsigned w, float e, float* acc) {
#if HAVE_FP8_CVT
    v2f lo = __builtin_amdgcn_cvt_pk_f32_fp8((int)w, false);
    v2f hi = __builtin_amdgcn_cvt_pk_f32_fp8((int)w, true);
    acc[0] = fmaf(e, lo[0], acc[0]); acc[1] = fmaf(e, lo[1], acc[1]);
    acc[2] = fmaf(e, hi[0], acc[2]); acc[3] = fmaf(e, hi[1], acc[3]);
#else
    acc[0] = fmaf(e, f8_dec1(w & 0xff), acc[0]);
    acc[1] = fmaf(e, f8_dec1((w >> 8) & 0xff), acc[1]);
    acc[2] = fmaf(e, f8_dec1((w >> 16) & 0xff), acc[2]);
    acc[3] = fmaf(e, f8_dec1(w >> 24), acc[3]);
#endif
}
// pack 8 bf16 (uint4) -> 8 fp8 (uint2)
__device__ __forceinline__ uint2 pack8(uint4 t) {
#if HAVE_FP8_CVT
    int u0 = __builtin_amdgcn_cvt_pk_fp8_f32(b2f_lo(t.x), b2f_hi(t.x), 0, false);
    u0 = __builtin_amdgcn_cvt_pk_fp8_f32(b2f_lo(t.y), b2f_hi(t.y), u0, true);
    int u1 = __builtin_amdgcn_cvt_pk_fp8_f32(b2f_lo(t.z), b2f_hi(t.z), 0, false);
    u1 = __builtin_amdgcn_cvt_pk_fp8_f32(b2f_lo(t.w), b2f_hi(t.w), u1, true);
    return make_uint2((unsigned)u0, (unsigned)u1);
#else
    unsigned u0 = f8_enc1(b2f_lo(t.x)) | (f8_enc1(b2f_hi(t.x)) << 8)
                | (f8_enc1(b2f_lo(t.y)) << 16) | (f8_enc1(b2f_hi(t.y)) << 24);
    unsigned u1 = f8_enc1(b2f_lo(t.z)) | (f8_enc1(b2f_hi(t.z)) << 8)
                | (f8_enc1(b2f_lo(t.w)) << 16) | (f8_enc1(b2f_hi(t.w)) << 24);
    return make_uint2(u0, u1);
#endif
}

__global__ void ws_sentinel_kernel(float* out, int bucket)
{
    if (threadIdx.x == 0) out[0] = ldexpf(1.f + (float)bucket / 256.f, 100);
}

// =====================================================================
// K0: gather weights/biases into one contiguous fp32 block.
// =====================================================================
__global__ __launch_bounds__(256) void convert_weights(
    const float* Wq, const float* Wk, const float* Wv, const float* Wo,
    const float* bq, const float* bk, const float* bv, const float* bo,
    const float* ga, const float* be,
    float* __restrict__ dst)
{
    int idx = blockIdx.x * 256 + threadIdx.x;
    if (idx >= CW_TOTAL) return;
    const float* src; int loc;
    if      (idx < CW_WK) { src = Wq; loc = idx - CW_WQ; }
    else if (idx < CW_WV) { src = Wk; loc = idx - CW_WK; }
    else if (idx < CW_WO) { src = Wv; loc = idx - CW_WV; }
    else if (idx < CW_BQ) { src = Wo; loc = idx - CW_WO; }
    else if (idx < CW_BK) { src = bq; loc = idx - CW_BQ; }
    else if (idx < CW_BV) { src = bk; loc = idx - CW_BK; }
    else if (idx < CW_BO) { src = bv; loc = idx - CW_BV; }
    else if (idx < CW_GA) { src = bo; loc = idx - CW_BO; }
    else if (idx < CW_BE) { src = ga; loc = idx - CW_GA; }
    else                  { src = be; loc = idx - CW_BE; }
    dst[idx] = src[loc];
}

// =====================================================================
// K0c: pack Wq/Wk/Wv' into MFMA B-fragment-major bf16 (R8-verified).
// =====================================================================
__global__ __launch_bounds__(256) void pack_wfrag(
    const float* __restrict__ cw, unsigned short* __restrict__ wfrag)
{
    int g = blockIdx.x * 256 + threadIdx.x;
    if (g >= 3 * 5 * 8 * 64) return;
    int lane = g & 63;
    int nt   = (g >> 6) & 7;
    int mk   = g >> 9;
    int kc = mk % 5, mat = mk / 5;
    int quad = lane >> 4, l15 = lane & 15;
    int n = nt * 16 + l15;

    unsigned short* dst = wfrag + (size_t)g * 8;
    #pragma unroll
    for (int j = 0; j < 8; ++j) {
        int k = kc * 32 + quad * 8 + j;
        float v = 0.f;
        if (mat == 0)      { if (k < TDIM) v = cw[CW_WQ + k * HDIM + n]; }
        else if (mat == 1) { if (k < TDIM) v = cw[CW_WK + k * HDIM + n]; }
        else               { if (k >= PDIM && k < TDIM) v = cw[CW_WV + (k - PDIM) * HDIM + n]; }
        dst[j] = f2b(v);
    }
}

// =====================================================================
// K1-MFMA: fused Q,K,V GEMMs (R9 structure).  Q -> bf16; K,V -> FP8.
// =====================================================================
__global__ __launch_bounds__(256) void qkv_mfma_kernel(
    const float* __restrict__ physics, const float* __restrict__ emb,
    const float* __restrict__ cw, const unsigned short* __restrict__ wfrag,
    unsigned short* __restrict__ Qb, unsigned char* __restrict__ K8,
    unsigned char* __restrict__ V8, int n_nodes)
{
    __shared__ __align__(16) unsigned short smem[SMEM_SH];

    const int tid = threadIdx.x;
    const int nbase = blockIdx.x * 64;
    const int lane = tid & 63;
    const int w = tid >> 6;
    const int quad = lane >> 4;
    const int l15 = lane & 15;

    uint4 breg[10];
    {
        const uint4* gsrc = (const uint4*)wfrag;
        #pragma unroll
        for (int i = 0; i < 10; ++i) breg[i] = gsrc[i * 256 + tid];
    }

    for (int idx = tid; idx < 64 * 84; idx += 256) {
        int r = idx / 84, p = idx - r * 84;
        int node = nbase + r;
        float v0 = 0.f, v1 = 0.f;
        if (node < n_nodes) {
            int k = 2 * p;
            if (k + 1 < PDIM) {
                const float* ph = physics + node * PDIM + k;
                v0 = ph[0]; v1 = ph[1];
            } else if (k < TDIM) {
                const float* em = emb + (size_t)node * HDIM + (k - PDIM);
                v0 = em[0]; v1 = em[1];
            }
        }
        ((unsigned*)smem)[r * 84 + p] = (unsigned)f2b(v0) | ((unsigned)f2b(v1) << 16);
    }

    {
        uint4* bdst = (uint4*)(smem + B_SH);
        #pragma unroll
        for (int i = 0; i < 10; ++i) bdst[i * 256 + tid] = breg[i];
    }
    __syncthreads();

    v8s a_frag[5];
    #pragma unroll
    for (int kc = 0; kc < 5; ++kc)
        a_frag[kc] = *(v8s*)(smem + (w * 16 + l15) * AROW + kc * 32 + quad * 8);

    const int r_out = tid >> 2;
    const int cseg = (tid & 3) * 32;
    const int node_out = nbase + r_out;

    for (int mat = 0; mat < 3; ++mat) {
        if (mat < 2) {
            const uint4* gsrc = (const uint4*)(wfrag + (size_t)(mat + 1) * B_LEN);
            #pragma unroll
            for (int i = 0; i < 10; ++i) breg[i] = gsrc[i * 256 + tid];
        }

        v4f acc[8];
        #pragma unroll
        for (int nt = 0; nt < 8; ++nt) acc[nt] = (v4f){0.f, 0.f, 0.f, 0.f};

        #pragma unroll
        for (int kc = 0; kc < 5; ++kc) {
            #pragma unroll
            for (int nt = 0; nt < 8; ++nt) {
                v8s b = *(v8s*)(smem + B_SH + ((kc * 8 + nt) * 64 + lane) * 8);
                acc[nt] = __builtin_amdgcn_mfma_f32_16x16x32_bf16(
                    a_frag[kc], b, acc[nt], 0, 0, 0);
            }
        }

        #pragma unroll
        for (int nt = 0; nt < 8; ++nt) {
            float bias = cw[CW_BQ + mat * HDIM + nt * 16 + l15];
            #pragma unroll
            for (int reg = 0; reg < 4; ++reg) {
                int row = w * 16 + quad * 4 + reg;
                smem[T_SH + row * TROW + nt * 16 + l15] = f2b(acc[nt][reg] + bias);
            }
        }
        __syncthreads();

        if (node_out < n_nodes) {
            const unsigned short* srcp = smem + T_SH + r_out * TROW + cseg;
            if (mat == 0) {
                unsigned short* dst = Qb + (size_t)node_out * HDIM + cseg;
                #pragma unroll
                for (int j = 0; j < 4; ++j)
                    ((uint4*)dst)[j] = *(const uint4*)(srcp + 8 * j);
            } else {
                unsigned char* dst8 = (mat == 1 ? K8 : V8) + (size_t)node_out * HDIM + cseg;
                uint4 t0 = *(const uint4*)(srcp);
                uint4 t1 = *(const uint4*)(srcp + 8);
                uint4 t2 = *(const uint4*)(srcp + 16);
                uint4 t3 = *(const uint4*)(srcp + 24);
                uint2 p0 = pack8(t0), p1 = pack8(t1), p2 = pack8(t2), p3 = pack8(t3);
                ((uint4*)dst8)[0] = make_uint4(p0.x, p0.y, p1.x, p1.y);
                ((uint4*)dst8)[1] = make_uint4(p2.x, p2.y, p3.x, p3.y);
            }
        }
        if (mat < 2) {
            uint4* bdst = (uint4*)(smem + B_SH);
            #pragma unroll
            for (int i = 0; i < 10; ++i) bdst[i * 256 + tid] = breg[i];
        }
        __syncthreads();
    }
}

// =====================================================================
// CSR build (unchanged)
// =====================================================================
__global__ __launch_bounds__(256) void degree_kernel(
    const int* __restrict__ ei, int* __restrict__ deg, int n_edges, int n_nodes)
{
    int e = blockIdx.x * 256 + threadIdx.x;
    if (e < n_edges) {
        int d = ei[n_edges + e];
        d = max(0, min(d, n_nodes - 1));
        atomicAdd(&deg[d], 1);
    }
}

__global__ __launch_bounds__(256) void scan_bsum(
    const int* __restrict__ deg, int* __restrict__ bsum, int n)
{
    __shared__ int s[256];
    int i = blockIdx.x * 256 + threadIdx.x;
    s[threadIdx.x] = (i < n) ? deg[i] : 0;
    __syncthreads();
    for (int off = 128; off > 0; off >>= 1) {
        if (threadIdx.x < off) s[threadIdx.x] += s[threadIdx.x + off];
        __syncthreads();
    }
    if (threadIdx.x == 0) bsum[blockIdx.x] = s[0];
}

__global__ __launch_bounds__(512) void scan_boff(
    const int* __restrict__ bsum, int* __restrict__ boff, int nb)
{
    __shared__ int s[512];
    int t = threadIdx.x;
    int v = (t < nb) ? bsum[t] : 0;
    s[t] = v;
    __syncthreads();
    for (int off = 1; off < 512; off <<= 1) {
        int u = (t >= off) ? s[t - off] : 0;
        __syncthreads();
        s[t] += u;
        __syncthreads();
    }
    if (t < nb) boff[t] = s[t] - v;
}

__global__ __launch_bounds__(256) void scan_final(
    const int* __restrict__ deg, const int* __restrict__ boff,
    int* __restrict__ row_off, int n)
{
    __shared__ int s[256];
    int t = threadIdx.x;
    int i = blockIdx.x * 256 + t;
    int v = (i < n) ? deg[i] : 0;
    s[t] = v;
    __syncthreads();
    for (int off = 1; off < 256; off <<= 1) {
        int u = (t >= off) ? s[t - off] : 0;
        __syncthreads();
        s[t] += u;
        __syncthreads();
    }
    int base = boff[blockIdx.x];
    if (i < n) row_off[i] = base + s[t] - v;
    if (i == n - 1) row_off[n] = base + s[t];
}

__global__ __launch_bounds__(256) void fill_kernel(
    const int* __restrict__ ei, const int* __restrict__ row_off,
    int* __restrict__ cursor, int* __restrict__ csr_src, int n_edges, int n_nodes)
{
    int e = blockIdx.x * 256 + threadIdx.x;
    if (e < n_edges) {
        int d = ei[n_edges + e];
        d = max(0, min(d, n_nodes - 1));
        int pos = atomicAdd(&cursor[d], 1);
        csr_src[row_off[d] + pos] = ei[e];
    }
}

// =====================================================================
// K5 v3: FUSED attention over FP8 K/V.  One wave per dst node.
// eg = lane>>3 (8 edge slots), cg = lane&7 (16 channels each).
// Per batch: uint4 K + uint4 V (fp8) per lane -> 8 edges in flight.
// Dot reduce over cg (xor 1,2,4); combine over eg (xor 8,16,32).
// =====================================================================
__global__ __launch_bounds__(256) void attn_fused_kernel(
    const unsigned short* __restrict__ Qb, const unsigned char* __restrict__ K8,
    const unsigned char* __restrict__ V8,
    const int* __restrict__ row_off, const int* __restrict__ csr_src,
    float* __restrict__ agg, int n_nodes, int n_edges)
{
    const int wid = (int)((blockIdx.x * 256 + threadIdx.x) >> 6);
    const int lane = threadIdx.x & 63;
    if (wid >= n_nodes) return;
    const int eg = lane >> 3;
    const int cg = lane & 7;

    const float scale = 0.088388347648318447f;   // 1/sqrt(128)
    const uint4* qp = (const uint4*)(Qb + (size_t)wid * HDIM + cg * 16);
    uint4 qa = qp[0], qb = qp[1];
    float q[16];
    q[0]  = b2f_lo(qa.x) * scale; q[1]  = b2f_hi(qa.x) * scale;
    q[2]  = b2f_lo(qa.y) * scale; q[3]  = b2f_hi(qa.y) * scale;
    q[4]  = b2f_lo(qa.z) * scale; q[5]  = b2f_hi(qa.z) * scale;
    q[6]  = b2f_lo(qa.w) * scale; q[7]  = b2f_hi(qa.w) * scale;
    q[8]  = b2f_lo(qb.x) * scale; q[9]  = b2f_hi(qb.x) * scale;
    q[10] = b2f_lo(qb.y) * scale; q[11] = b2f_hi(qb.y) * scale;
    q[12] = b2f_lo(qb.z) * scale; q[13] = b2f_hi(qb.z) * scale;
    q[14] = b2f_lo(qb.w) * scale; q[15] = b2f_hi(qb.w) * scale;

    int beg = row_off[wid], end = row_off[wid + 1];
    beg = max(0, min(beg, n_edges));
    end = max(beg, min(end, n_edges));

    float acc[16];
    #pragma unroll
    for (int j = 0; j < 16; ++j) acc[j] = 0.f;
    float den = 0.f;

    for (int i = beg; i < end; i += 8) {
        int idx = i + eg;
        bool valid = idx < end;
        int s = csr_src[valid ? idx : (end - 1)];
        s = max(0, min(s, n_nodes - 1));
        uint4 kr = *(const uint4*)(K8 + (size_t)s * HDIM + cg * 16);
        uint4 vr = *(const uint4*)(V8 + (size_t)s * HDIM + cg * 16);

        float p = 0.f;
        dot4(kr.x, q + 0, p);
        dot4(kr.y, q + 4, p);
        dot4(kr.z, q + 8, p);
        dot4(kr.w, q + 12, p);
        p += __shfl_xor(p, 1);
        p += __shfl_xor(p, 2);
        p += __shfl_xor(p, 4);

        float e = valid ? __expf(fminf(p, 60.f)) : 0.f;
        den += e;
        acc4(vr.x, e, acc + 0);
        acc4(vr.y, e, acc + 4);
        acc4(vr.z, e, acc + 8);
        acc4(vr.w, e, acc + 12);
    }

    #pragma unroll
    for (int j = 0; j < 16; ++j) {
        acc[j] += __shfl_xor(acc[j], 8);
        acc[j] += __shfl_xor(acc[j], 16);
        acc[j] += __shfl_xor(acc[j], 32);
    }
    den += __shfl_xor(den, 8);
    den += __shfl_xor(den, 16);
    den += __shfl_xor(den, 32);

    float inv = 1.f / (den + 1e-8f);
    if (eg == 0) {
        float* dst = agg + (size_t)wid * HDIM + cg * 16;
        #pragma unroll
        for (int j = 0; j < 4; ++j)
            *(float4*)(dst + 4 * j) = make_float4(acc[4*j] * inv, acc[4*j+1] * inv,
                                                 acc[4*j+2] * inv, acc[4*j+3] * inv);
    }
}

// =====================================================================
// K6: out = agg@Wo + bo; x = emb + out; LayerNorm -> FP32 d_out in-place.
// =====================================================================
__global__ __launch_bounds__(256) void out_ln_kernel(
    const float* __restrict__ emb,
    const float* __restrict__ cw,
    float* __restrict__ out, int n_nodes)
{
    __shared__ float lds[HDIM * 32];
    const int tid = threadIdx.x;
    const int nbase = blockIdx.x * 32;

    for (int idx = tid; idx < 32 * HDIM; idx += 256) {
        int m = idx >> 7;
        int t = idx & 127;
        int node = nbase + m;
        lds[t * 32 + m] = (node < n_nodes) ? out[(size_t)node * HDIM + t] : 0.f;
    }
    __syncthreads();

    const int c = tid & 31;
    const int g = tid >> 5;
    const float* Wo = cw + CW_WO;

    float acc[4][4] = {{0.f}};
    for (int t = 0; t < HDIM; ++t) {
        float4 r = *(const float4*)(lds + t * 32 + 4 * g);
        float rr[4] = { r.x, r.y, r.z, r.w };
        float4 w4 = *(const float4*)(Wo + t * HDIM + 4 * c);
        float wa[4] = { w4.x, w4.y, w4.z, w4.w };
        #pragma unroll
        for (int m = 0; m < 4; ++m)
            #pragma unroll
            for (int j = 0; j < 4; ++j)
                acc[m][j] = fmaf(rr[m], wa[j], acc[m][j]);
    }

    float4 bo4 = *(const float4*)(cw + CW_BO + 4 * c);
    float4 ga4 = *(const float4*)(cw + CW_GA + 4 * c);
    float4 be4 = *(const float4*)(cw + CW_BE + 4 * c);
    float boa[4] = { bo4.x, bo4.y, bo4.z, bo4.w };
    float ga[4]  = { ga4.x, ga4.y, ga4.z, ga4.w };
    float ba[4]  = { be4.x, be4.y, be4.z, be4.w };

    #pragma unroll
    for (int m = 0; m < 4; ++m) {
        int node = nbase + 4 * g + m;
        float ea[4] = { 0.f, 0.f, 0.f, 0.f };
        if (node < n_nodes) {
            float4 e4 = *(const float4*)(emb + (size_t)node * HDIM + 4 * c);
            ea[0] = e4.x; ea[1] = e4.y; ea[2] = e4.z; ea[3] = e4.w;
        }

        float x[4], s1 = 0.f, s2 = 0.f;
        #pragma unroll
        for (int j = 0; j < 4; ++j) {
            x[j] = ea[j] + acc[m][j] + boa[j];
            s1 += x[j];
            s2 = fmaf(x[j], x[j], s2);
        }
        #pragma unroll
        for (int mask = 1; mask <= 16; mask <<= 1) {
            s1 += __shfl_xor(s1, mask);
            s2 += __shfl_xor(s2, mask);
        }
        float mu = s1 * (1.f / 128.f);
        float var = fmaxf(s2 * (1.f / 128.f) - mu * mu, 0.f);
        float rs = rsqrtf(var + 1e-5f);
        if (node < n_nodes) {
            float4 o;
            o.x = ga[0] * (x[0] - mu) * rs + ba[0];
            o.y = ga[1] * (x[1] - mu) * rs + ba[1];
            o.z = ga[2] * (x[2] - mu) * rs + ba[2];
            o.w = ga[3] * (x[3] - mu) * rs + ba[3];
            *(float4*)(out + (size_t)node * HDIM + 4 * c) = o;
        }
    }
}

// =====================================================================
extern "C" void kernel_launch(void* const* d_in, const int* in_sizes, int n_in,
                              void* d_out, int out_size, void* d_ws, size_t ws_size,
                              hipStream_t stream)
{
    const float* physics = (const float*)d_in[0];
    const float* emb     = (const float*)d_in[1];
    const int*   ei      = (const int*)d_in[2];

    const int n_nodes = in_sizes[1] / HDIM;
    const int n_edges = in_sizes[2] / 2;
    const int NB = (n_nodes + 255) / 256;

    char* ws = (char*)d_ws;
    size_t off = 0;
    auto alloc = [&](size_t bytes) -> void* {
        void* p = ws + off;
        off = (off + bytes + 255) & ~(size_t)255;
        return p;
    };

    float* cw      = (float*)alloc((size_t)CW_TOTAL * 4);
    unsigned short* wfrag = (unsigned short*)alloc((size_t)3 * B_LEN * 2);
    int* deg       = (int*)alloc((size_t)2 * n_nodes * 4);
    int* cursor    = deg + n_nodes;
    int* row_off   = (int*)alloc((size_t)(n_nodes + 1) * 4);
    int* bsum      = (int*)alloc((size_t)NB * 4);
    int* boff      = (int*)alloc((size_t)NB * 4);
    int* csr_src   = (int*)alloc((size_t)n_edges * 4);
    unsigned short* Qb = (unsigned short*)alloc((size_t)n_nodes * HDIM * 2);
    unsigned char* K8  = (unsigned char*)alloc((size_t)n_nodes * HDIM);
    unsigned char* V8  = (unsigned char*)alloc((size_t)n_nodes * HDIM);

    if (ws_size < off) {   // ~60 MB needed; R7-R9 proved >= 85 MB available
        int bucket = (int)min((size_t)255, ws_size >> 24);
        ws_sentinel_kernel<<<1, 64, 0, stream>>>((float*)d_out, bucket);
        return;
    }

    hipMemsetAsync(deg, 0, (size_t)2 * n_nodes * sizeof(int), stream);

    convert_weights<<<(CW_TOTAL + 255) / 256, 256, 0, stream>>>(
        (const float*)d_in[3], (const float*)d_in[5], (const float*)d_in[7],
        (const float*)d_in[9], (const float*)d_in[4], (const float*)d_in[6],
        (const float*)d_in[8], (const float*)d_in[10], (const float*)d_in[11],
        (const float*)d_in[12], cw);

    pack_wfrag<<<(3 * 5 * 8 * 64 + 255) / 256, 256, 0, stream>>>(cw, wfrag);
    qkv_mfma_kernel<<<(n_nodes + 63) / 64, 256, 0, stream>>>(
        physics, emb, cw, wfrag, Qb, K8, V8, n_nodes);

    degree_kernel<<<(n_edges + 255) / 256, 256, 0, stream>>>(ei, deg, n_edges, n_nodes);
    scan_bsum<<<NB, 256, 0, stream>>>(deg, bsum, n_nodes);
    scan_boff<<<1, 512, 0, stream>>>(bsum, boff, NB);
    scan_final<<<NB, 256, 0, stream>>>(deg, boff, row_off, n_nodes);
    fill_kernel<<<(n_edges + 255) / 256, 256, 0, stream>>>(ei, row_off, cursor, csr_src, n_edges, n_nodes);

    attn_fused_kernel<<<(n_nodes + 3) / 4, 256, 0, stream>>>(
        Qb, K8, V8, row_off, csr_src, (float*)d_out, n_nodes, n_edges);

    out_ln_kernel<<<(n_nodes + 31) / 32, 256, 0, stream>>>(
        emb, cw, (float*)d_out, n_nodes);
}